// Round 2
// baseline (4322.511 us; speedup 1.0000x reference)
//
#include <hip/hip_runtime.h>
#include <math.h>

// Problem constants
constexpr int Bc  = 4;
constexpr int Cc  = 64;
constexpr int Hc  = 96;
constexpr int Wc  = 320;
constexpr int HWc = Hc * Wc;          // 30720
constexpr int NPIX = Bc * HWc;        // 122880

// Workspace layout (floats). Total = 19,212,544 floats = ~76.9 MB.
constexpr size_t OFF_WT1  = 0;         // [ci][kk][co]   64*9*64  = 36864
constexpr size_t OFF_WT2  = 36864;     // [ci][kk][co32] 64*9*32  = 18432 (co padded 27->32)
constexpr size_t OFF_WTD  = 55296;     // [k][c][o]      9*64*64  = 36864
constexpr size_t OFF_WTF  = 92160;     // [ci][kk][co]   128*9*64 = 73728
constexpr size_t OFF_AB   = 165888;    // A1[64],B1[64],A2[64],B2[64] = 256
constexpr size_t OFF_T    = 166144;    // t / h buffer: 4*64*96*320 = 7864320
constexpr size_t OFF_HEAD = 8030464;   // head: 4*27*96*320 = 3317760
constexpr size_t OFF_FD   = 11348224;  // fd:   4*64*96*320 = 7864320

// ---------------------------------------------------------------- prep ----
__global__ void prep_k(const float* __restrict__ w1, const float* __restrict__ b1,
                       const float* __restrict__ g1, const float* __restrict__ be1,
                       const float* __restrict__ m1, const float* __restrict__ v1,
                       const float* __restrict__ w2,
                       const float* __restrict__ wd,
                       const float* __restrict__ wf, const float* __restrict__ bf1,
                       const float* __restrict__ g2, const float* __restrict__ be2,
                       const float* __restrict__ m2, const float* __restrict__ v2,
                       float* __restrict__ ws) {
    int tid    = blockIdx.x * blockDim.x + threadIdx.x;
    int stride = gridDim.x * blockDim.x;
    // w_off1 (64,64,3,3) -> [ci][kk][co]
    for (int i = tid; i < 36864; i += stride) {
        int co = i & 63; int r = i >> 6; int kk = r % 9; int ci = r / 9;
        ws[OFF_WT1 + i] = w1[(co * 64 + ci) * 9 + kk];
    }
    // w_off2 (27,64,3,3) -> [ci][kk][co] padded to 32
    for (int i = tid; i < 18432; i += stride) {
        int co = i & 31; int r = i >> 5; int kk = r % 9; int ci = r / 9;
        ws[OFF_WT2 + i] = (co < 27) ? w2[(co * 64 + ci) * 9 + kk] : 0.f;
    }
    // w_def (64,64,3,3) -> [k][c][o]
    for (int i = tid; i < 36864; i += stride) {
        int o = i & 63; int r = i >> 6; int c = r & 63; int k = r >> 6;
        ws[OFF_WTD + i] = wd[(o * 64 + c) * 9 + k];
    }
    // w_f1 (64,128,3,3) -> [ci][kk][co]
    for (int i = tid; i < 73728; i += stride) {
        int co = i & 63; int r = i >> 6; int kk = r % 9; int ci = r / 9;
        ws[OFF_WTF + i] = wf[(co * 128 + ci) * 9 + kk];
    }
    // BN folds
    if (tid < 64) {
        float s1 = g1[tid] / sqrtf(v1[tid] + 1e-5f);
        ws[OFF_AB + tid]       = s1;
        ws[OFF_AB + 64 + tid]  = b1[tid] * s1 + be1[tid] - m1[tid] * s1;
        float s2 = g2[tid] / sqrtf(v2[tid] + 1e-5f);
        ws[OFF_AB + 128 + tid] = s2;
        ws[OFF_AB + 192 + tid] = bf1[tid] * s2 + be2[tid] - m2[tid] * s2;
    }
}

// -------------------------------------------------- conv1 (64->64) + BN ----
__global__ __launch_bounds__(256) void conv1_k(const float* __restrict__ x,
                                               const float* __restrict__ ws,
                                               float* __restrict__ t) {
    __shared__ __align__(16) float wl[4608];   // 8 ci * 9 kk * 64 co
    int p  = blockIdx.x * 256 + threadIdx.x;
    int xw = p % Wc; int rem = p / Wc; int y = rem % Hc; int b = rem / Hc;
    float acc[64];
#pragma unroll
    for (int i = 0; i < 64; ++i) acc[i] = 0.f;
    const float* xb = x + (size_t)b * Cc * HWc;
    for (int cic = 0; cic < 8; ++cic) {
        __syncthreads();
        const float* src = ws + OFF_WT1 + (size_t)cic * 4608;
        for (int i = threadIdx.x; i < 4608; i += 256) wl[i] = src[i];
        __syncthreads();
#pragma unroll 1
        for (int ci8 = 0; ci8 < 8; ++ci8) {
            const float* xc = xb + (cic * 8 + ci8) * HWc;
#pragma unroll
            for (int kk = 0; kk < 9; ++kk) {
                int iy = y + kk / 3 - 1, ix = xw + kk % 3 - 1;
                float xv = (iy >= 0 && iy < Hc && ix >= 0 && ix < Wc) ? xc[iy * Wc + ix] : 0.f;
                const float* wp = &wl[(ci8 * 9 + kk) * 64];
#pragma unroll
                for (int q = 0; q < 16; ++q) {
                    float4 w4 = *(const float4*)(wp + q * 4);
                    acc[q * 4 + 0] = fmaf(xv, w4.x, acc[q * 4 + 0]);
                    acc[q * 4 + 1] = fmaf(xv, w4.y, acc[q * 4 + 1]);
                    acc[q * 4 + 2] = fmaf(xv, w4.z, acc[q * 4 + 2]);
                    acc[q * 4 + 3] = fmaf(xv, w4.w, acc[q * 4 + 3]);
                }
            }
        }
    }
    const float* A1 = ws + OFF_AB;
    const float* B1 = ws + OFF_AB + 64;
    float* tb = t + (size_t)b * Cc * HWc + y * Wc + xw;
#pragma unroll
    for (int co = 0; co < 64; ++co) tb[co * HWc] = fmaf(acc[co], A1[co], B1[co]);
}

// -------------------------------------------------- conv2 (64->27) head ----
__global__ __launch_bounds__(256) void conv2_k(const float* __restrict__ ws,
                                               const float* __restrict__ b2,
                                               float* __restrict__ head) {
    __shared__ __align__(16) float wl[4608];   // 16 ci * 9 kk * 32 co
    const float* t = ws + OFF_T;
    int p  = blockIdx.x * 256 + threadIdx.x;
    int xw = p % Wc; int rem = p / Wc; int y = rem % Hc; int b = rem / Hc;
    float acc[32];
#pragma unroll
    for (int i = 0; i < 32; ++i) acc[i] = 0.f;
    const float* xb = t + (size_t)b * Cc * HWc;
    for (int cic = 0; cic < 4; ++cic) {
        __syncthreads();
        const float* src = ws + OFF_WT2 + (size_t)cic * 4608;
        for (int i = threadIdx.x; i < 4608; i += 256) wl[i] = src[i];
        __syncthreads();
#pragma unroll 1
        for (int ci16 = 0; ci16 < 16; ++ci16) {
            const float* xc = xb + (cic * 16 + ci16) * HWc;
#pragma unroll
            for (int kk = 0; kk < 9; ++kk) {
                int iy = y + kk / 3 - 1, ix = xw + kk % 3 - 1;
                float xv = (iy >= 0 && iy < Hc && ix >= 0 && ix < Wc) ? xc[iy * Wc + ix] : 0.f;
                const float* wp = &wl[(ci16 * 9 + kk) * 32];
#pragma unroll
                for (int q = 0; q < 8; ++q) {
                    float4 w4 = *(const float4*)(wp + q * 4);
                    acc[q * 4 + 0] = fmaf(xv, w4.x, acc[q * 4 + 0]);
                    acc[q * 4 + 1] = fmaf(xv, w4.y, acc[q * 4 + 1]);
                    acc[q * 4 + 2] = fmaf(xv, w4.z, acc[q * 4 + 2]);
                    acc[q * 4 + 3] = fmaf(xv, w4.w, acc[q * 4 + 3]);
                }
            }
        }
    }
    float* hb = head + (size_t)b * 27 * HWc + y * Wc + xw;
#pragma unroll
    for (int co = 0; co < 27; ++co) hb[co * HWc] = acc[co] + b2[co];
}

// ------------------------------------ mdcn + residual add (writes fd) ----
__global__ __launch_bounds__(256) void mdcn_k(const float* __restrict__ xd,
                                              const float* __restrict__ ws,
                                              const float* __restrict__ bd,
                                              float* __restrict__ fd) {
    __shared__ __align__(16) float wl[4096];   // w_def[k]: [c][o] 64*64
    const float* head = ws + OFF_HEAD;
    int p  = blockIdx.x * 256 + threadIdx.x;
    int xw = p % Wc; int rem = p / Wc; int y = rem % Hc; int b = rem / Hc;
    float acc[64];
#pragma unroll
    for (int i = 0; i < 64; ++i) acc[i] = 0.f;
    const float* xb = xd + (size_t)b * Cc * HWc;
    const float* hb = head + (size_t)b * 27 * HWc + y * Wc + xw;
#pragma unroll 1
    for (int k = 0; k < 9; ++k) {
        __syncthreads();
        const float* src = ws + OFF_WTD + (size_t)k * 4096;
        for (int i = threadIdx.x; i < 4096; i += 256) wl[i] = src[i];
        __syncthreads();
        float dy = hb[(2 * k) * HWc];
        float dx = hb[(2 * k + 1) * HWc];
        float sm = hb[(18 + k) * HWc];
        float m  = 1.f / (1.f + expf(-sm));
        float py = (float)(y + k / 3 - 1) + dy;
        float px = (float)(xw + k % 3 - 1) + dx;
        float y0f = floorf(py), x0f = floorf(px);
        float wy = py - y0f, wx = px - x0f;
        int y0 = (int)y0f, x0 = (int)x0f;
        int y1 = y0 + 1, x1 = x0 + 1;
        bool vy0 = ((unsigned)y0 < (unsigned)Hc), vy1 = ((unsigned)y1 < (unsigned)Hc);
        bool vx0 = ((unsigned)x0 < (unsigned)Wc), vx1 = ((unsigned)x1 < (unsigned)Wc);
        int cy0 = min(max(y0, 0), Hc - 1), cy1 = min(max(y1, 0), Hc - 1);
        int cx0 = min(max(x0, 0), Wc - 1), cx1 = min(max(x1, 0), Wc - 1);
        float w00 = (vy0 && vx0) ? (1.f - wy) * (1.f - wx) * m : 0.f;
        float w01 = (vy0 && vx1) ? (1.f - wy) * wx * m : 0.f;
        float w10 = (vy1 && vx0) ? wy * (1.f - wx) * m : 0.f;
        float w11 = (vy1 && vx1) ? wy * wx * m : 0.f;
        int i00 = cy0 * Wc + cx0, i01 = cy0 * Wc + cx1;
        int i10 = cy1 * Wc + cx0, i11 = cy1 * Wc + cx1;
#pragma unroll 1
        for (int c = 0; c < 64; ++c) {
            const float* f = xb + c * HWc;
            float v = w00 * f[i00] + w01 * f[i01] + w10 * f[i10] + w11 * f[i11];
            const float* wp = &wl[c * 64];
#pragma unroll
            for (int q = 0; q < 16; ++q) {
                float4 w4 = *(const float4*)(wp + q * 4);
                acc[q * 4 + 0] = fmaf(v, w4.x, acc[q * 4 + 0]);
                acc[q * 4 + 1] = fmaf(v, w4.y, acc[q * 4 + 1]);
                acc[q * 4 + 2] = fmaf(v, w4.z, acc[q * 4 + 2]);
                acc[q * 4 + 3] = fmaf(v, w4.w, acc[q * 4 + 3]);
            }
        }
    }
    const float* xo = xb + y * Wc + xw;
    float* fo = fd + (size_t)b * Cc * HWc + y * Wc + xw;
#pragma unroll
    for (int o = 0; o < 64; ++o) fo[o * HWc] = xo[o * HWc] + acc[o] + bd[o];
}

// ------------------------------- conv_f1 (128->64) + BN + relu (-> h) ----
__global__ __launch_bounds__(256) void convf_k(const float* __restrict__ xrgb,
                                               const float* __restrict__ ws,
                                               float* __restrict__ h) {
    __shared__ __align__(16) float wl[4608];   // 8 ci * 9 kk * 64 co
    const float* fdp = ws + OFF_FD;
    int p  = blockIdx.x * 256 + threadIdx.x;
    int xw = p % Wc; int rem = p / Wc; int y = rem % Hc; int b = rem / Hc;
    float acc[64];
#pragma unroll
    for (int i = 0; i < 64; ++i) acc[i] = 0.f;
    for (int cic = 0; cic < 16; ++cic) {
        __syncthreads();
        const float* src = ws + OFF_WTF + (size_t)cic * 4608;
        for (int i = threadIdx.x; i < 4608; i += 256) wl[i] = src[i];
        __syncthreads();
#pragma unroll 1
        for (int ci8 = 0; ci8 < 8; ++ci8) {
            int ci = cic * 8 + ci8;
            const float* xc = (ci < 64) ? (fdp + (size_t)b * Cc * HWc + ci * HWc)
                                        : (xrgb + (size_t)b * Cc * HWc + (ci - 64) * HWc);
#pragma unroll
            for (int kk = 0; kk < 9; ++kk) {
                int iy = y + kk / 3 - 1, ix = xw + kk % 3 - 1;
                float xv = (iy >= 0 && iy < Hc && ix >= 0 && ix < Wc) ? fmaxf(xc[iy * Wc + ix], 0.f) : 0.f;
                const float* wp = &wl[(ci8 * 9 + kk) * 64];
#pragma unroll
                for (int q = 0; q < 16; ++q) {
                    float4 w4 = *(const float4*)(wp + q * 4);
                    acc[q * 4 + 0] = fmaf(xv, w4.x, acc[q * 4 + 0]);
                    acc[q * 4 + 1] = fmaf(xv, w4.y, acc[q * 4 + 1]);
                    acc[q * 4 + 2] = fmaf(xv, w4.z, acc[q * 4 + 2]);
                    acc[q * 4 + 3] = fmaf(xv, w4.w, acc[q * 4 + 3]);
                }
            }
        }
    }
    const float* A2 = ws + OFF_AB + 128;
    const float* B2 = ws + OFF_AB + 192;
    float* ho = h + (size_t)b * Cc * HWc + y * Wc + xw;
#pragma unroll
    for (int co = 0; co < 64; ++co) ho[co * HWc] = fmaxf(fmaf(acc[co], A2[co], B2[co]), 0.f);
}

// ------------------------------------------------- conv_out (64->1) ----
__global__ __launch_bounds__(256) void convo_k(const float* __restrict__ ws,
                                               const float* __restrict__ wo,
                                               const float* __restrict__ bo,
                                               float* __restrict__ out) {
    __shared__ float wl[576];
    const float* h = ws + OFF_T;
    for (int i = threadIdx.x; i < 576; i += 256) wl[i] = wo[i];
    __syncthreads();
    int p  = blockIdx.x * 256 + threadIdx.x;
    int xw = p % Wc; int rem = p / Wc; int y = rem % Hc; int b = rem / Hc;
    float acc = bo[0];
    const float* hb = h + (size_t)b * Cc * HWc;
#pragma unroll 1
    for (int ci = 0; ci < 64; ++ci) {
        const float* xc = hb + ci * HWc;
#pragma unroll
        for (int kk = 0; kk < 9; ++kk) {
            int iy = y + kk / 3 - 1, ix = xw + kk % 3 - 1;
            float xv = (iy >= 0 && iy < Hc && ix >= 0 && ix < Wc) ? xc[iy * Wc + ix] : 0.f;
            acc = fmaf(xv, wl[ci * 9 + kk], acc);
        }
    }
    out[p] = acc;
}

// ------------------------------------------------------------ launch ----
extern "C" void kernel_launch(void* const* d_in, const int* in_sizes, int n_in,
                              void* d_out, int out_size, void* d_ws, size_t ws_size,
                              hipStream_t stream) {
    const float* feat_rgb   = (const float*)d_in[0];
    const float* feat_depth = (const float*)d_in[1];
    const float* w_off1 = (const float*)d_in[2];
    const float* b_off1 = (const float*)d_in[3];
    const float* g1  = (const float*)d_in[4];
    const float* be1 = (const float*)d_in[5];
    const float* m1  = (const float*)d_in[6];
    const float* v1  = (const float*)d_in[7];
    const float* w_off2 = (const float*)d_in[8];
    const float* b_off2 = (const float*)d_in[9];
    const float* w_def  = (const float*)d_in[10];
    const float* b_def  = (const float*)d_in[11];
    const float* w_f1   = (const float*)d_in[12];
    const float* b_f1   = (const float*)d_in[13];
    const float* g2  = (const float*)d_in[14];
    const float* be2 = (const float*)d_in[15];
    const float* m2  = (const float*)d_in[16];
    const float* v2  = (const float*)d_in[17];
    const float* w_out = (const float*)d_in[18];
    const float* b_out = (const float*)d_in[19];

    float* ws = (float*)d_ws;   // needs ~77 MB
    (void)ws_size; (void)in_sizes; (void)n_in; (void)out_size;

    prep_k<<<288, 256, 0, stream>>>(w_off1, b_off1, g1, be1, m1, v1,
                                    w_off2, w_def, w_f1, b_f1, g2, be2, m2, v2, ws);
    const int nblk = NPIX / 256;  // 480
    conv1_k<<<nblk, 256, 0, stream>>>(feat_rgb, ws, ws + OFF_T);
    conv2_k<<<nblk, 256, 0, stream>>>(ws, b_off2, ws + OFF_HEAD);
    mdcn_k <<<nblk, 256, 0, stream>>>(feat_depth, ws, b_def, ws + OFF_FD);
    convf_k<<<nblk, 256, 0, stream>>>(feat_rgb, ws, ws + OFF_T);
    convo_k<<<nblk, 256, 0, stream>>>(ws, w_out, b_out, (float*)d_out);
}

// Round 3
// 576.220 us; speedup vs baseline: 7.5015x; 7.5015x over previous
//
#include <hip/hip_runtime.h>
#include <math.h>

// ---------------- problem constants ----------------
constexpr int Bc  = 4;
constexpr int Hc  = 96;
constexpr int Wc  = 320;
constexpr int HWc = Hc * Wc;           // 30720
constexpr int NPIX = Bc * HWc;         // 122880

typedef __attribute__((ext_vector_type(8))) short short8;   // 8 x bf16 fragment
typedef __attribute__((ext_vector_type(4))) float f32x4;    // mfma acc

// ---------------- workspace byte offsets ----------------
// all 256-aligned; total ~63.3 MB (fits known-good 77MB budget)
constexpr size_t B_W1   = 0;                    // bf16 [9][64co][64ci]   73728 B
constexpr size_t B_W2   = 73728;                // bf16 [9][32co][64ci]   36864 B
constexpr size_t B_WD   = 110592;               // bf16 [9][64o][64c]     73728 B
constexpr size_t B_WF   = 184320;               // bf16 [2][9][64co][64ci]147456 B
constexpr size_t B_AB   = 331776;               // f32 A1,B1,A2,B2        1024 B
constexpr size_t B_RGBT = 332800;               // bf16 [pix][64]         15728640 B
constexpr size_t B_DEPT = 16061440;             // bf16 [pix][64]  (later reused as hT)
constexpr size_t B_TT   = 31790080;             // bf16 [pix][64]  (later reused as fdreluT)
constexpr size_t B_HEAD = 47518720;             // f32  [pix][32]         15728640 B

// ---------------- helpers ----------------
static __device__ __forceinline__ unsigned short f2bf(float f) {
    unsigned u = __builtin_bit_cast(unsigned, f);
    u = (u + 0x7fffu + ((u >> 16) & 1u)) >> 16;   // RNE
    return (unsigned short)u;
}
static __device__ __forceinline__ float bf2f(unsigned short h) {
    unsigned u = ((unsigned)h) << 16;
    return __builtin_bit_cast(float, u);
}

// ---------------- prep: weights + BN folds ----------------
__global__ void prep_w(const float* __restrict__ w1, const float* __restrict__ b1,
                       const float* __restrict__ g1, const float* __restrict__ be1,
                       const float* __restrict__ m1, const float* __restrict__ v1,
                       const float* __restrict__ w2,
                       const float* __restrict__ wd,
                       const float* __restrict__ wf, const float* __restrict__ bf1,
                       const float* __restrict__ g2, const float* __restrict__ be2,
                       const float* __restrict__ m2, const float* __restrict__ v2,
                       char* __restrict__ ws) {
    int tid = blockIdx.x * blockDim.x + threadIdx.x;
    int stride = gridDim.x * blockDim.x;
    unsigned short* W1 = (unsigned short*)(ws + B_W1);
    unsigned short* W2 = (unsigned short*)(ws + B_W2);
    unsigned short* WD = (unsigned short*)(ws + B_WD);
    unsigned short* WF = (unsigned short*)(ws + B_WF);
    float* AB = (float*)(ws + B_AB);
    for (int i = tid; i < 36864; i += stride) {         // W1p [kk][co][ci]
        int ci = i & 63, co = (i >> 6) & 63, kk = i >> 12;
        W1[i] = f2bf(w1[(co * 64 + ci) * 9 + kk]);
    }
    for (int i = tid; i < 18432; i += stride) {         // W2p [kk][32co][ci]
        int ci = i & 63, co = (i >> 6) & 31, kk = i >> 11;
        W2[i] = (co < 27) ? f2bf(w2[(co * 64 + ci) * 9 + kk]) : (unsigned short)0;
    }
    for (int i = tid; i < 36864; i += stride) {         // Wdp [kk][o][c]
        int c = i & 63, o = (i >> 6) & 63, kk = i >> 12;
        WD[i] = f2bf(wd[(o * 64 + c) * 9 + kk]);
    }
    for (int i = tid; i < 73728; i += stride) {         // Wfp [half][kk][co][ci]
        int ci = i & 63, co = (i >> 6) & 63, r = i >> 12;
        int kk = r % 9, h = r / 9;
        WF[i] = f2bf(wf[(co * 128 + h * 64 + ci) * 9 + kk]);
    }
    if (tid < 64) {
        float s1 = g1[tid] / sqrtf(v1[tid] + 1e-5f);
        AB[tid]        = s1;
        AB[64 + tid]   = b1[tid] * s1 + be1[tid] - m1[tid] * s1;
        float s2 = g2[tid] / sqrtf(v2[tid] + 1e-5f);
        AB[128 + tid]  = s2;
        AB[192 + tid]  = bf1[tid] * s2 + be2[tid] - m2[tid] * s2;
    }
}

// ---------------- prep: transpose inputs to pixel-major bf16 ----------------
__global__ __launch_bounds__(256) void prep_x(const float* __restrict__ rgb,
                                              const float* __restrict__ dep,
                                              unsigned short* __restrict__ rgbT,
                                              unsigned short* __restrict__ depT) {
    int i = blockIdx.x * 256 + threadIdx.x;     // over NPIX*8
    if (i >= NPIX * 8) return;
    int g = i & 7;                 // ci-group (8 channels)
    int pg = i >> 3;               // flat pixel 0..122879
    int b = pg / HWc, p = pg % HWc;
    size_t sb = (size_t)b * 64 * HWc + p + (size_t)(g * 8) * HWc;
    unsigned short r8[8], d8[8];
#pragma unroll
    for (int j = 0; j < 8; ++j) {
        r8[j] = f2bf(rgb[sb + (size_t)j * HWc]);
        d8[j] = f2bf(dep[sb + (size_t)j * HWc]);
    }
    *(short8*)(rgbT + (size_t)pg * 64 + g * 8) = *(short8*)r8;
    *(short8*)(depT + (size_t)pg * 64 + g * 8) = *(short8*)d8;
}

// ---------------- LDS staging for conv tiles ----------------
// LDS layout: [3 rows][66 xx][64 ci] bf16, byte addr ^= ((xx&7)<<4)
static __device__ __forceinline__ void stage_tile(const unsigned short* __restrict__ src,
                                                  int b, int y0, int x0,
                                                  unsigned short* lds, bool do_relu) {
#pragma unroll
    for (int it = 0; it < 7; ++it) {
        int i = threadIdx.x + it * 256;
        if (i < 1584) {
            int g = i & 7;
            int xx = (i >> 3) % 66;
            int row = (i >> 3) / 66;
            int y = y0 - 1 + row, x = x0 - 1 + xx;
            short8 v = (short8)0;
            if ((unsigned)y < 96u && (unsigned)x < 320u) {
                v = *(const short8*)(src + ((size_t)(b * HWc + y * Wc + x)) * 64 + g * 8);
            }
            if (do_relu) {
#pragma unroll
                for (int j = 0; j < 8; ++j) {
                    short s = v[j];
                    v[j] = (s & (short)0x8000) ? (short)0 : s;
                }
            }
            int byte = ((row * 66 + xx) * 64 + g * 8) * 2;
            byte ^= ((xx & 7) << 4);
            *(short8*)((char*)lds + byte) = v;
        }
    }
}

static __device__ __forceinline__ short8 read_b(const unsigned short* lds, int row, int xx, int cofs) {
    int byte = ((row * 66 + xx) * 64 + cofs) * 2;
    byte ^= ((xx & 7) << 4);
    return *(const short8*)((const char*)lds + byte);
}

// ---------------- conv1: 64->64 + BN, rgbT -> tT ----------------
__global__ __launch_bounds__(256) void conv1_m(const unsigned short* __restrict__ rgbT,
                                               const char* __restrict__ ws,
                                               unsigned short* __restrict__ tT) {
    __shared__ __align__(16) unsigned short xls[3 * 66 * 64];
    const unsigned short* W1 = (const unsigned short*)(ws + B_W1);
    const float* AB = (const float*)(ws + B_AB);
    int blk = blockIdx.x;
    int xt = blk % 5, y = (blk / 5) % 96, b = blk / 480;
    int x0 = xt * 64;
    stage_tile(rgbT, b, y, x0, xls, false);
    __syncthreads();
    int lane = threadIdx.x & 63, w = threadIdx.x >> 6;
    int pl = lane & 15, q4 = lane >> 4;
    int p = w * 16 + pl;
    f32x4 acc[4];
#pragma unroll
    for (int cp = 0; cp < 4; ++cp) acc[cp] = (f32x4)0.f;
#pragma unroll
    for (int kk = 0; kk < 9; ++kk) {
        int dy = kk / 3, dx = kk % 3;
        int xx = p + dx;
#pragma unroll
        for (int ch = 0; ch < 2; ++ch) {
            short8 bfr = read_b(xls, dy, xx, ch * 32 + q4 * 8);
#pragma unroll
            for (int cp = 0; cp < 4; ++cp) {
                short8 afr = *(const short8*)(W1 + ((kk * 64 + cp * 16 + pl) * 64 + ch * 32 + q4 * 8));
                acc[cp] = __builtin_amdgcn_mfma_f32_16x16x32_bf16(afr, bfr, acc[cp], 0, 0, 0);
            }
        }
    }
    size_t pglob = (size_t)(b * HWc + y * Wc + x0 + p);
#pragma unroll
    for (int cp = 0; cp < 4; ++cp) {
        int co0 = cp * 16 + q4 * 4;
        f32x4 a1 = *(const f32x4*)(AB + co0);
        f32x4 b1 = *(const f32x4*)(AB + 64 + co0);
        unsigned short h4[4];
#pragma unroll
        for (int j = 0; j < 4; ++j) h4[j] = f2bf(fmaf(acc[cp][j], a1[j], b1[j]));
        uint2 u;
        u.x = (unsigned)h4[0] | ((unsigned)h4[1] << 16);
        u.y = (unsigned)h4[2] | ((unsigned)h4[3] << 16);
        *(uint2*)(tT + pglob * 64 + co0) = u;
    }
}

// ---------------- conv2: 64->27(pad 32), tT -> headT (f32) ----------------
__global__ __launch_bounds__(256) void conv2_m(const char* __restrict__ ws,
                                               const float* __restrict__ b2,
                                               float* __restrict__ headT,
                                               const unsigned short* __restrict__ tT) {
    __shared__ __align__(16) unsigned short xls[3 * 66 * 64];
    const unsigned short* W2 = (const unsigned short*)(ws + B_W2);
    int blk = blockIdx.x;
    int xt = blk % 5, y = (blk / 5) % 96, b = blk / 480;
    int x0 = xt * 64;
    stage_tile(tT, b, y, x0, xls, false);
    __syncthreads();
    int lane = threadIdx.x & 63, w = threadIdx.x >> 6;
    int pl = lane & 15, q4 = lane >> 4;
    int cp = w & 1;              // co-part (0/1)
    int pg0 = (w >> 1) * 2;      // two pixgroups per wave
    f32x4 acc[2];
    acc[0] = (f32x4)0.f; acc[1] = (f32x4)0.f;
#pragma unroll
    for (int kk = 0; kk < 9; ++kk) {
        int dy = kk / 3, dx = kk % 3;
#pragma unroll
        for (int ch = 0; ch < 2; ++ch) {
            short8 afr = *(const short8*)(W2 + ((kk * 32 + cp * 16 + pl) * 64 + ch * 32 + q4 * 8));
#pragma unroll
            for (int s = 0; s < 2; ++s) {
                int p = (pg0 + s) * 16 + pl;
                short8 bfr = read_b(xls, dy, p + dx, ch * 32 + q4 * 8);
                acc[s] = __builtin_amdgcn_mfma_f32_16x16x32_bf16(afr, bfr, acc[s], 0, 0, 0);
            }
        }
    }
#pragma unroll
    for (int s = 0; s < 2; ++s) {
        int p = (pg0 + s) * 16 + pl;
        size_t pglob = (size_t)(b * HWc + y * Wc + x0 + p);
        int co0 = cp * 16 + q4 * 4;
        f32x4 r;
#pragma unroll
        for (int j = 0; j < 4; ++j) {
            float bias = (co0 + j < 27) ? b2[co0 + j] : 0.f;
            r[j] = acc[s][j] + bias;
        }
        *(f32x4*)(headT + pglob * 32 + co0) = r;
    }
}

// ---------------- mdcn: deformable sampling + 576-K GEMM -> fdreluT ----------------
__global__ __launch_bounds__(256) void mdcn_m(const float* __restrict__ feat_depth,
                                              const unsigned short* __restrict__ depthT,
                                              const float* __restrict__ headT,
                                              const char* __restrict__ ws,
                                              const float* __restrict__ bd,
                                              unsigned short* __restrict__ fdreluT) {
    __shared__ __align__(16) unsigned short vls[64 * 64];   // val tile [pix][c] swizzled
    const unsigned short* WD = (const unsigned short*)(ws + B_WD);
    int blk = blockIdx.x;
    int xt = blk % 5, y = (blk / 5) % 96, b = blk / 480;
    int x0 = xt * 64;
    int lane = threadIdx.x & 63, w = threadIdx.x >> 6;
    int pl = lane & 15, q4 = lane >> 4;
    // val production mapping
    int vp = threadIdx.x & 63;      // pixel 0..63
    int cq = threadIdx.x >> 6;      // c-quarter (16 ch)
    int px = x0 + vp;
    size_t pglob_v = (size_t)(b * HWc + y * Wc + px);
    const float* hd = headT + pglob_v * 32;
    size_t dbase = (size_t)b * HWc * 64;
    f32x4 acc[4];
#pragma unroll
    for (int cp = 0; cp < 4; ++cp) acc[cp] = (f32x4)0.f;

    for (int kk = 0; kk < 9; ++kk) {
        if (kk) __syncthreads();    // WAR: previous GEMM reads done
        // ---- produce val[vp][cq*16 .. +15] ----
        float dyv = hd[2 * kk], dxv = hd[2 * kk + 1], sm = hd[18 + kk];
        float m = 1.f / (1.f + __expf(-sm));
        float py = (float)(y + kk / 3 - 1) + dyv;
        float pxf = (float)(px + kk % 3 - 1) + dxv;
        float y0f = floorf(py), x0f = floorf(pxf);
        float wy = py - y0f, wx = pxf - x0f;
        int iy0 = (int)y0f, ix0 = (int)x0f;
        bool vy0 = (unsigned)iy0 < 96u, vy1 = (unsigned)(iy0 + 1) < 96u;
        bool vx0 = (unsigned)ix0 < 320u, vx1 = (unsigned)(ix0 + 1) < 320u;
        int cy0 = min(max(iy0, 0), 95), cy1 = min(max(iy0 + 1, 0), 95);
        int cx0 = min(max(ix0, 0), 319), cx1 = min(max(ix0 + 1, 0), 319);
        float w00 = (vy0 && vx0) ? (1.f - wy) * (1.f - wx) * m : 0.f;
        float w01 = (vy0 && vx1) ? (1.f - wy) * wx * m : 0.f;
        float w10 = (vy1 && vx0) ? wy * (1.f - wx) * m : 0.f;
        float w11 = (vy1 && vx1) ? wy * wx * m : 0.f;
        const unsigned short* p00 = depthT + dbase + (size_t)(cy0 * Wc + cx0) * 64 + cq * 16;
        const unsigned short* p01 = depthT + dbase + (size_t)(cy0 * Wc + cx1) * 64 + cq * 16;
        const unsigned short* p10 = depthT + dbase + (size_t)(cy1 * Wc + cx0) * 64 + cq * 16;
        const unsigned short* p11 = depthT + dbase + (size_t)(cy1 * Wc + cx1) * 64 + cq * 16;
        short8 f00l = *(const short8*)p00, f00h = *(const short8*)(p00 + 8);
        short8 f01l = *(const short8*)p01, f01h = *(const short8*)(p01 + 8);
        short8 f10l = *(const short8*)p10, f10h = *(const short8*)(p10 + 8);
        short8 f11l = *(const short8*)p11, f11h = *(const short8*)(p11 + 8);
        unsigned short vlo[8], vhi[8];
#pragma unroll
        for (int j = 0; j < 8; ++j) {
            float v = w00 * bf2f((unsigned short)f00l[j]) + w01 * bf2f((unsigned short)f01l[j])
                    + w10 * bf2f((unsigned short)f10l[j]) + w11 * bf2f((unsigned short)f11l[j]);
            vlo[j] = f2bf(v);
        }
#pragma unroll
        for (int j = 0; j < 8; ++j) {
            float v = w00 * bf2f((unsigned short)f00h[j]) + w01 * bf2f((unsigned short)f01h[j])
                    + w10 * bf2f((unsigned short)f10h[j]) + w11 * bf2f((unsigned short)f11h[j]);
            vhi[j] = f2bf(v);
        }
        int e0 = (vp * 64 + cq * 16) * 2;
        *(short8*)((char*)vls + (e0 ^ ((vp & 7) << 4)))        = *(short8*)vlo;
        *(short8*)((char*)vls + ((e0 + 16) ^ ((vp & 7) << 4))) = *(short8*)vhi;
        __syncthreads();
        // ---- GEMM: acc += Wd[kk] * val ----
        int xxp = w * 16 + pl;      // local pixel
#pragma unroll
        for (int ch = 0; ch < 2; ++ch) {
            int byte = ((xxp * 64 + ch * 32 + q4 * 8) * 2) ^ ((xxp & 7) << 4);
            short8 bfr = *(const short8*)((const char*)vls + byte);
#pragma unroll
            for (int cp = 0; cp < 4; ++cp) {
                short8 afr = *(const short8*)(WD + ((kk * 64 + cp * 16 + pl) * 64 + ch * 32 + q4 * 8));
                acc[cp] = __builtin_amdgcn_mfma_f32_16x16x32_bf16(afr, bfr, acc[cp], 0, 0, 0);
            }
        }
    }
    // epilogue: fdrelu = relu(acc + bd + feat_depth) -> bf16 [pix][64]
    int p = w * 16 + pl;
    int pix = y * Wc + x0 + p;
    size_t pglob = (size_t)(b * HWc) + pix;
#pragma unroll
    for (int cp = 0; cp < 4; ++cp) {
        int co0 = cp * 16 + q4 * 4;
        f32x4 bdv = *(const f32x4*)(bd + co0);
        unsigned short h4[4];
#pragma unroll
        for (int j = 0; j < 4; ++j) {
            float r = acc[cp][j] + bdv[j] + feat_depth[((size_t)b * 64 + co0 + j) * HWc + pix];
            h4[j] = f2bf(fmaxf(r, 0.f));
        }
        uint2 u;
        u.x = (unsigned)h4[0] | ((unsigned)h4[1] << 16);
        u.y = (unsigned)h4[2] | ((unsigned)h4[3] << 16);
        *(uint2*)(fdreluT + pglob * 64 + co0) = u;
    }
}

// ---------------- convf: 128->64 + BN + relu -> hT ----------------
__global__ __launch_bounds__(256) void convf_m(const unsigned short* __restrict__ fdreluT,
                                               const unsigned short* __restrict__ rgbT,
                                               const char* __restrict__ ws,
                                               unsigned short* __restrict__ hT) {
    __shared__ __align__(16) unsigned short xls[3 * 66 * 64];
    const unsigned short* WF = (const unsigned short*)(ws + B_WF);
    const float* AB = (const float*)(ws + B_AB);
    int blk = blockIdx.x;
    int xt = blk % 5, y = (blk / 5) % 96, b = blk / 480;
    int x0 = xt * 64;
    int lane = threadIdx.x & 63, w = threadIdx.x >> 6;
    int pl = lane & 15, q4 = lane >> 4;
    int p = w * 16 + pl;
    f32x4 acc[4];
#pragma unroll
    for (int cp = 0; cp < 4; ++cp) acc[cp] = (f32x4)0.f;
#pragma unroll
    for (int half = 0; half < 2; ++half) {
        if (half) __syncthreads();
        stage_tile(half ? rgbT : fdreluT, b, y, x0, xls, half != 0);
        __syncthreads();
        const unsigned short* Wh = WF + half * 36864;
#pragma unroll
        for (int kk = 0; kk < 9; ++kk) {
            int dy = kk / 3, dx = kk % 3;
            int xx = p + dx;
#pragma unroll
            for (int ch = 0; ch < 2; ++ch) {
                short8 bfr = read_b(xls, dy, xx, ch * 32 + q4 * 8);
#pragma unroll
                for (int cp = 0; cp < 4; ++cp) {
                    short8 afr = *(const short8*)(Wh + ((kk * 64 + cp * 16 + pl) * 64 + ch * 32 + q4 * 8));
                    acc[cp] = __builtin_amdgcn_mfma_f32_16x16x32_bf16(afr, bfr, acc[cp], 0, 0, 0);
                }
            }
        }
    }
    size_t pglob = (size_t)(b * HWc + y * Wc + x0 + p);
#pragma unroll
    for (int cp = 0; cp < 4; ++cp) {
        int co0 = cp * 16 + q4 * 4;
        f32x4 a2 = *(const f32x4*)(AB + 128 + co0);
        f32x4 b2 = *(const f32x4*)(AB + 192 + co0);
        unsigned short h4[4];
#pragma unroll
        for (int j = 0; j < 4; ++j) h4[j] = f2bf(fmaxf(fmaf(acc[cp][j], a2[j], b2[j]), 0.f));
        uint2 u;
        u.x = (unsigned)h4[0] | ((unsigned)h4[1] << 16);
        u.y = (unsigned)h4[2] | ((unsigned)h4[3] << 16);
        *(uint2*)(hT + pglob * 64 + co0) = u;
    }
}

// ---------------- conv_out: 64->1 ----------------
__global__ __launch_bounds__(256) void convo_m(const unsigned short* __restrict__ hT,
                                               const float* __restrict__ wo,
                                               const float* __restrict__ bo,
                                               float* __restrict__ out) {
    __shared__ float wl[576];
    for (int i = threadIdx.x; i < 576; i += 256) wl[i] = wo[i];
    __syncthreads();
    int p = blockIdx.x * 256 + threadIdx.x;   // 0..122879
    int xw = p % Wc, rem = p / Wc, y = rem % Hc, b = rem / Hc;
    float acc = bo[0];
#pragma unroll
    for (int kk = 0; kk < 9; ++kk) {
        int iy = y + kk / 3 - 1, ix = xw + kk % 3 - 1;
        if ((unsigned)iy < 96u && (unsigned)ix < 320u) {
            const unsigned short* base = hT + ((size_t)(b * HWc + iy * Wc + ix)) * 64;
#pragma unroll
            for (int g = 0; g < 8; ++g) {
                short8 v = *(const short8*)(base + g * 8);
#pragma unroll
                for (int j = 0; j < 8; ++j)
                    acc = fmaf(bf2f((unsigned short)v[j]), wl[(g * 8 + j) * 9 + kk], acc);
            }
        }
    }
    out[p] = acc;
}

// ---------------- launch ----------------
extern "C" void kernel_launch(void* const* d_in, const int* in_sizes, int n_in,
                              void* d_out, int out_size, void* d_ws, size_t ws_size,
                              hipStream_t stream) {
    const float* feat_rgb   = (const float*)d_in[0];
    const float* feat_depth = (const float*)d_in[1];
    const float* w_off1 = (const float*)d_in[2];
    const float* b_off1 = (const float*)d_in[3];
    const float* g1  = (const float*)d_in[4];
    const float* be1 = (const float*)d_in[5];
    const float* m1  = (const float*)d_in[6];
    const float* v1  = (const float*)d_in[7];
    const float* w_off2 = (const float*)d_in[8];
    const float* b_off2 = (const float*)d_in[9];
    const float* w_def  = (const float*)d_in[10];
    const float* b_def  = (const float*)d_in[11];
    const float* w_f1   = (const float*)d_in[12];
    const float* b_f1   = (const float*)d_in[13];
    const float* g2  = (const float*)d_in[14];
    const float* be2 = (const float*)d_in[15];
    const float* m2  = (const float*)d_in[16];
    const float* v2  = (const float*)d_in[17];
    const float* w_out = (const float*)d_in[18];
    const float* b_out = (const float*)d_in[19];
    (void)in_sizes; (void)n_in; (void)out_size; (void)ws_size;

    char* ws = (char*)d_ws;
    unsigned short* rgbT   = (unsigned short*)(ws + B_RGBT);
    unsigned short* depthT = (unsigned short*)(ws + B_DEPT);
    unsigned short* tT     = (unsigned short*)(ws + B_TT);
    float*          headT  = (float*)(ws + B_HEAD);
    unsigned short* fdreluT = tT;       // reuse (tT dead after conv2)
    unsigned short* hT      = depthT;   // reuse (depthT dead after mdcn)

    prep_w<<<64, 256, 0, stream>>>(w_off1, b_off1, g1, be1, m1, v1,
                                   w_off2, w_def, w_f1, b_f1, g2, be2, m2, v2, ws);
    prep_x<<<(NPIX * 8 + 255) / 256, 256, 0, stream>>>(feat_rgb, feat_depth, rgbT, depthT);
    conv1_m<<<1920, 256, 0, stream>>>(rgbT, ws, tT);
    conv2_m<<<1920, 256, 0, stream>>>(ws, b_off2, headT, tT);
    mdcn_m <<<1920, 256, 0, stream>>>(feat_depth, depthT, headT, ws, b_def, fdreluT);
    convf_m<<<1920, 256, 0, stream>>>(fdreluT, rgbT, ws, hT);
    convo_m<<<480, 256, 0, stream>>>(hT, w_out, b_out, (float*)d_out);
}

// Round 4
// 547.783 us; speedup vs baseline: 7.8909x; 1.0519x over previous
//
#include <hip/hip_runtime.h>
#include <math.h>

// ---------------- problem constants ----------------
constexpr int Bc  = 4;
constexpr int Hc  = 96;
constexpr int Wc  = 320;
constexpr int HWc = Hc * Wc;           // 30720
constexpr int NPIX = Bc * HWc;         // 122880

typedef __attribute__((ext_vector_type(8))) short short8;   // 8 x bf16 fragment
typedef __attribute__((ext_vector_type(4))) float f32x4;    // mfma acc

// ---------------- workspace byte offsets ----------------
constexpr size_t B_W1   = 0;                    // bf16 [9][64co][64ci]   73728 B
constexpr size_t B_W2   = 73728;                // bf16 [9][32co][64ci]   36864 B
constexpr size_t B_WD   = 110592;               // bf16 [9][64o][64c]     73728 B
constexpr size_t B_WF   = 184320;               // bf16 [2][9][64co][64ci]147456 B
constexpr size_t B_AB   = 331776;               // f32 A1,B1,A2,B2        1024 B
constexpr size_t B_RGBT = 332800;               // bf16 [pix][64]         15728640 B
constexpr size_t B_DEPT = 16061440;             // bf16 [pix][64]  (later reused as hT)
constexpr size_t B_TT   = 31790080;             // bf16 [pix][64]  (later reused as fdreluT)
constexpr size_t B_HEAD = 47518720;             // f32  [pix][32]         15728640 B

// ---------------- helpers ----------------
static __device__ __forceinline__ unsigned short f2bf(float f) {
    unsigned u = __builtin_bit_cast(unsigned, f);
    u = (u + 0x7fffu + ((u >> 16) & 1u)) >> 16;   // RNE
    return (unsigned short)u;
}
static __device__ __forceinline__ float bf2f(unsigned short h) {
    unsigned u = ((unsigned)h) << 16;
    return __builtin_bit_cast(float, u);
}
// XCD-aware block swizzle: grid must be divisible by 8. Each XCD gets a
// contiguous chunk of the work-index space -> gather/halo re-reads L2-hit.
static __device__ __forceinline__ int swz_blk(int bid, int chunk) {
    return (bid & 7) * chunk + (bid >> 3);
}

// ---------------- prep: weights + BN folds ----------------
__global__ void prep_w(const float* __restrict__ w1, const float* __restrict__ b1,
                       const float* __restrict__ g1, const float* __restrict__ be1,
                       const float* __restrict__ m1, const float* __restrict__ v1,
                       const float* __restrict__ w2,
                       const float* __restrict__ wd,
                       const float* __restrict__ wf, const float* __restrict__ bf1,
                       const float* __restrict__ g2, const float* __restrict__ be2,
                       const float* __restrict__ m2, const float* __restrict__ v2,
                       char* __restrict__ ws) {
    int tid = blockIdx.x * blockDim.x + threadIdx.x;
    int stride = gridDim.x * blockDim.x;
    unsigned short* W1 = (unsigned short*)(ws + B_W1);
    unsigned short* W2 = (unsigned short*)(ws + B_W2);
    unsigned short* WD = (unsigned short*)(ws + B_WD);
    unsigned short* WF = (unsigned short*)(ws + B_WF);
    float* AB = (float*)(ws + B_AB);
    for (int i = tid; i < 36864; i += stride) {         // W1p [kk][co][ci]
        int ci = i & 63, co = (i >> 6) & 63, kk = i >> 12;
        W1[i] = f2bf(w1[(co * 64 + ci) * 9 + kk]);
    }
    for (int i = tid; i < 18432; i += stride) {         // W2p [kk][32co][ci]
        int ci = i & 63, co = (i >> 6) & 31, kk = i >> 11;
        W2[i] = (co < 27) ? f2bf(w2[(co * 64 + ci) * 9 + kk]) : (unsigned short)0;
    }
    for (int i = tid; i < 36864; i += stride) {         // Wdp [kk][o][c]
        int c = i & 63, o = (i >> 6) & 63, kk = i >> 12;
        WD[i] = f2bf(wd[(o * 64 + c) * 9 + kk]);
    }
    for (int i = tid; i < 73728; i += stride) {         // Wfp [half][kk][co][ci]
        int ci = i & 63, co = (i >> 6) & 63, r = i >> 12;
        int kk = r % 9, h = r / 9;
        WF[i] = f2bf(wf[(co * 128 + h * 64 + ci) * 9 + kk]);
    }
    if (tid < 64) {
        float s1 = g1[tid] / sqrtf(v1[tid] + 1e-5f);
        AB[tid]        = s1;
        AB[64 + tid]   = b1[tid] * s1 + be1[tid] - m1[tid] * s1;
        float s2 = g2[tid] / sqrtf(v2[tid] + 1e-5f);
        AB[128 + tid]  = s2;
        AB[192 + tid]  = bf1[tid] * s2 + be2[tid] - m2[tid] * s2;
    }
}

// ---------------- prep: transpose inputs to pixel-major bf16 ----------------
__global__ __launch_bounds__(256) void prep_x(const float* __restrict__ rgb,
                                              const float* __restrict__ dep,
                                              unsigned short* __restrict__ rgbT,
                                              unsigned short* __restrict__ depT) {
    int i = blockIdx.x * 256 + threadIdx.x;     // over NPIX*8
    if (i >= NPIX * 8) return;
    int g = i & 7;                 // ci-group (8 channels)
    int pg = i >> 3;               // flat pixel 0..122879
    int b = pg / HWc, p = pg % HWc;
    size_t sb = (size_t)b * 64 * HWc + p + (size_t)(g * 8) * HWc;
    unsigned short r8[8], d8[8];
#pragma unroll
    for (int j = 0; j < 8; ++j) {
        r8[j] = f2bf(rgb[sb + (size_t)j * HWc]);
        d8[j] = f2bf(dep[sb + (size_t)j * HWc]);
    }
    *(short8*)(rgbT + (size_t)pg * 64 + g * 8) = *(short8*)r8;
    *(short8*)(depT + (size_t)pg * 64 + g * 8) = *(short8*)d8;
}

// ---------------- LDS staging for conv tiles ----------------
// LDS layout: [3 rows][66 xx][64 ci] bf16, byte addr ^= ((xx&7)<<4)
static __device__ __forceinline__ void stage_tile(const unsigned short* __restrict__ src,
                                                  int b, int y0, int x0,
                                                  unsigned short* lds, bool do_relu) {
#pragma unroll
    for (int it = 0; it < 7; ++it) {
        int i = threadIdx.x + it * 256;
        if (i < 1584) {
            int g = i & 7;
            int xx = (i >> 3) % 66;
            int row = (i >> 3) / 66;
            int y = y0 - 1 + row, x = x0 - 1 + xx;
            short8 v = (short8)0;
            if ((unsigned)y < 96u && (unsigned)x < 320u) {
                v = *(const short8*)(src + ((size_t)(b * HWc + y * Wc + x)) * 64 + g * 8);
            }
            if (do_relu) {
#pragma unroll
                for (int j = 0; j < 8; ++j) {
                    short s = v[j];
                    v[j] = (s & (short)0x8000) ? (short)0 : s;
                }
            }
            int byte = ((row * 66 + xx) * 64 + g * 8) * 2;
            byte ^= ((xx & 7) << 4);
            *(short8*)((char*)lds + byte) = v;
        }
    }
}

static __device__ __forceinline__ short8 read_b(const unsigned short* lds, int row, int xx, int cofs) {
    int byte = ((row * 66 + xx) * 64 + cofs) * 2;
    byte ^= ((xx & 7) << 4);
    return *(const short8*)((const char*)lds + byte);
}

// ---------------- conv1: 64->64 + BN, rgbT -> tT ----------------
__global__ __launch_bounds__(256) void conv1_m(const unsigned short* __restrict__ rgbT,
                                               const char* __restrict__ ws,
                                               unsigned short* __restrict__ tT) {
    __shared__ __align__(16) unsigned short xls[3 * 66 * 64];
    const unsigned short* W1 = (const unsigned short*)(ws + B_W1);
    const float* AB = (const float*)(ws + B_AB);
    int blk = swz_blk(blockIdx.x, 240);
    int xt = blk % 5, y = (blk / 5) % 96, b = blk / 480;
    int x0 = xt * 64;
    stage_tile(rgbT, b, y, x0, xls, false);
    __syncthreads();
    int lane = threadIdx.x & 63, w = threadIdx.x >> 6;
    int pl = lane & 15, q4 = lane >> 4;
    int p = w * 16 + pl;
    f32x4 acc[4];
#pragma unroll
    for (int cp = 0; cp < 4; ++cp) acc[cp] = (f32x4)0.f;
#pragma unroll
    for (int kk = 0; kk < 9; ++kk) {
        int dy = kk / 3, dx = kk % 3;
        int xx = p + dx;
#pragma unroll
        for (int ch = 0; ch < 2; ++ch) {
            short8 bfr = read_b(xls, dy, xx, ch * 32 + q4 * 8);
#pragma unroll
            for (int cp = 0; cp < 4; ++cp) {
                short8 afr = *(const short8*)(W1 + ((kk * 64 + cp * 16 + pl) * 64 + ch * 32 + q4 * 8));
                acc[cp] = __builtin_amdgcn_mfma_f32_16x16x32_bf16(afr, bfr, acc[cp], 0, 0, 0);
            }
        }
    }
    size_t pglob = (size_t)(b * HWc + y * Wc + x0 + p);
#pragma unroll
    for (int cp = 0; cp < 4; ++cp) {
        int co0 = cp * 16 + q4 * 4;
        f32x4 a1 = *(const f32x4*)(AB + co0);
        f32x4 b1 = *(const f32x4*)(AB + 64 + co0);
        unsigned short h4[4];
#pragma unroll
        for (int j = 0; j < 4; ++j) h4[j] = f2bf(fmaf(acc[cp][j], a1[j], b1[j]));
        uint2 u;
        u.x = (unsigned)h4[0] | ((unsigned)h4[1] << 16);
        u.y = (unsigned)h4[2] | ((unsigned)h4[3] << 16);
        *(uint2*)(tT + pglob * 64 + co0) = u;
    }
}

// ---------------- conv2: 64->27(pad 32), tT -> headT (f32) ----------------
__global__ __launch_bounds__(256) void conv2_m(const char* __restrict__ ws,
                                               const float* __restrict__ b2,
                                               float* __restrict__ headT,
                                               const unsigned short* __restrict__ tT) {
    __shared__ __align__(16) unsigned short xls[3 * 66 * 64];
    const unsigned short* W2 = (const unsigned short*)(ws + B_W2);
    int blk = swz_blk(blockIdx.x, 240);
    int xt = blk % 5, y = (blk / 5) % 96, b = blk / 480;
    int x0 = xt * 64;
    stage_tile(tT, b, y, x0, xls, false);
    __syncthreads();
    int lane = threadIdx.x & 63, w = threadIdx.x >> 6;
    int pl = lane & 15, q4 = lane >> 4;
    int cp = w & 1;              // co-part (0/1)
    int pg0 = (w >> 1) * 2;      // two pixgroups per wave
    f32x4 acc[2];
    acc[0] = (f32x4)0.f; acc[1] = (f32x4)0.f;
#pragma unroll
    for (int kk = 0; kk < 9; ++kk) {
        int dy = kk / 3, dx = kk % 3;
#pragma unroll
        for (int ch = 0; ch < 2; ++ch) {
            short8 afr = *(const short8*)(W2 + ((kk * 32 + cp * 16 + pl) * 64 + ch * 32 + q4 * 8));
#pragma unroll
            for (int s = 0; s < 2; ++s) {
                int p = (pg0 + s) * 16 + pl;
                short8 bfr = read_b(xls, dy, p + dx, ch * 32 + q4 * 8);
                acc[s] = __builtin_amdgcn_mfma_f32_16x16x32_bf16(afr, bfr, acc[s], 0, 0, 0);
            }
        }
    }
#pragma unroll
    for (int s = 0; s < 2; ++s) {
        int p = (pg0 + s) * 16 + pl;
        size_t pglob = (size_t)(b * HWc + y * Wc + x0 + p);
        int co0 = cp * 16 + q4 * 4;
        f32x4 r;
#pragma unroll
        for (int j = 0; j < 4; ++j) {
            float bias = (co0 + j < 27) ? b2[co0 + j] : 0.f;
            r[j] = acc[s][j] + bias;
        }
        *(f32x4*)(headT + pglob * 32 + co0) = r;
    }
}

// ---- mdcn: register-direct bilinear + 576-K GEMM -> fdreluT (no LDS) ----
__global__ __launch_bounds__(256) void mdcn_r(const float* __restrict__ feat_depth,
                                              const unsigned short* __restrict__ depthT,
                                              const float* __restrict__ headT,
                                              const char* __restrict__ ws,
                                              const float* __restrict__ bd,
                                              unsigned short* __restrict__ fdreluT) {
    const unsigned short* WD = (const unsigned short*)(ws + B_WD);
    int blk = swz_blk(blockIdx.x, 240);
    int xt = blk % 5, y = (blk / 5) % 96, b = blk / 480;
    int x0 = xt * 64;
    int lane = threadIdx.x & 63, w = threadIdx.x >> 6;
    int pl = lane & 15, q4 = lane >> 4;
    int p = w * 16 + pl;           // local pixel (B column)
    int px = x0 + p;
    size_t pglob = (size_t)(b * HWc + y * Wc + px);
    size_t dbase = (size_t)b * HWc * 64;
    // preload all 27 head values for this pixel (q4-duplicated; L1 broadcast)
    const float* hd = headT + pglob * 32;
    float hv[28];
#pragma unroll
    for (int i = 0; i < 7; ++i) {
        f32x4 t = *(const f32x4*)(hd + i * 4);
        hv[i * 4 + 0] = t[0]; hv[i * 4 + 1] = t[1];
        hv[i * 4 + 2] = t[2]; hv[i * 4 + 3] = t[3];
    }
    f32x4 acc[4];
#pragma unroll
    for (int cp = 0; cp < 4; ++cp) acc[cp] = (f32x4)0.f;

#pragma unroll 3
    for (int kk = 0; kk < 9; ++kk) {
        float dyv = hv[2 * kk], dxv = hv[2 * kk + 1], sm = hv[18 + kk];
        float m = 1.f / (1.f + __expf(-sm));
        float py  = (float)(y + kk / 3 - 1) + dyv;
        float pxf = (float)(px + kk % 3 - 1) + dxv;
        float y0f = floorf(py), x0f = floorf(pxf);
        float wy = py - y0f, wx = pxf - x0f;
        int iy0 = (int)y0f, ix0 = (int)x0f;
        bool vy0 = (unsigned)iy0 < 96u, vy1 = (unsigned)(iy0 + 1) < 96u;
        bool vx0 = (unsigned)ix0 < 320u, vx1 = (unsigned)(ix0 + 1) < 320u;
        int cy0 = min(max(iy0, 0), 95), cy1 = min(max(iy0 + 1, 0), 95);
        int cx0 = min(max(ix0, 0), 319), cx1 = min(max(ix0 + 1, 0), 319);
        float w00 = (vy0 && vx0) ? (1.f - wy) * (1.f - wx) * m : 0.f;
        float w01 = (vy0 && vx1) ? (1.f - wy) * wx * m : 0.f;
        float w10 = (vy1 && vx0) ? wy * (1.f - wx) * m : 0.f;
        float w11 = (vy1 && vx1) ? wy * wx * m : 0.f;
        // this thread's K-slices: channels ch*32 + q4*8 .. +8 of its pixel
        const unsigned short* r00 = depthT + dbase + (size_t)(cy0 * Wc + cx0) * 64 + q4 * 8;
        const unsigned short* r01 = depthT + dbase + (size_t)(cy0 * Wc + cx1) * 64 + q4 * 8;
        const unsigned short* r10 = depthT + dbase + (size_t)(cy1 * Wc + cx0) * 64 + q4 * 8;
        const unsigned short* r11 = depthT + dbase + (size_t)(cy1 * Wc + cx1) * 64 + q4 * 8;
#pragma unroll
        for (int ch = 0; ch < 2; ++ch) {
            short8 f00 = *(const short8*)(r00 + ch * 32);
            short8 f01 = *(const short8*)(r01 + ch * 32);
            short8 f10 = *(const short8*)(r10 + ch * 32);
            short8 f11 = *(const short8*)(r11 + ch * 32);
            unsigned short vv[8];
#pragma unroll
            for (int j = 0; j < 8; ++j) {
                float v = w00 * bf2f((unsigned short)f00[j]) + w01 * bf2f((unsigned short)f01[j])
                        + w10 * bf2f((unsigned short)f10[j]) + w11 * bf2f((unsigned short)f11[j]);
                vv[j] = f2bf(v);
            }
            short8 bfr = *(short8*)vv;
#pragma unroll
            for (int cp = 0; cp < 4; ++cp) {
                short8 afr = *(const short8*)(WD + ((kk * 64 + cp * 16 + pl) * 64 + ch * 32 + q4 * 8));
                acc[cp] = __builtin_amdgcn_mfma_f32_16x16x32_bf16(afr, bfr, acc[cp], 0, 0, 0);
            }
        }
    }
    // epilogue: fdrelu = relu(acc + bd + feat_depth) -> bf16 [pix][64]
    int pix = y * Wc + px;
#pragma unroll
    for (int cp = 0; cp < 4; ++cp) {
        int co0 = cp * 16 + q4 * 4;
        f32x4 bdv = *(const f32x4*)(bd + co0);
        unsigned short h4[4];
#pragma unroll
        for (int j = 0; j < 4; ++j) {
            float r = acc[cp][j] + bdv[j] + feat_depth[((size_t)b * 64 + co0 + j) * HWc + pix];
            h4[j] = f2bf(fmaxf(r, 0.f));
        }
        uint2 u;
        u.x = (unsigned)h4[0] | ((unsigned)h4[1] << 16);
        u.y = (unsigned)h4[2] | ((unsigned)h4[3] << 16);
        *(uint2*)(fdreluT + ((size_t)(b * HWc) + pix) * 64 + co0) = u;
    }
}

// ---------------- convf: 128->64 + BN + relu -> hT ----------------
__global__ __launch_bounds__(256) void convf_m(const unsigned short* __restrict__ fdreluT,
                                               const unsigned short* __restrict__ rgbT,
                                               const char* __restrict__ ws,
                                               unsigned short* __restrict__ hT) {
    __shared__ __align__(16) unsigned short xls[3 * 66 * 64];
    const unsigned short* WF = (const unsigned short*)(ws + B_WF);
    const float* AB = (const float*)(ws + B_AB);
    int blk = swz_blk(blockIdx.x, 240);
    int xt = blk % 5, y = (blk / 5) % 96, b = blk / 480;
    int x0 = xt * 64;
    int lane = threadIdx.x & 63, w = threadIdx.x >> 6;
    int pl = lane & 15, q4 = lane >> 4;
    int p = w * 16 + pl;
    f32x4 acc[4];
#pragma unroll
    for (int cp = 0; cp < 4; ++cp) acc[cp] = (f32x4)0.f;
#pragma unroll
    for (int half = 0; half < 2; ++half) {
        if (half) __syncthreads();
        stage_tile(half ? rgbT : fdreluT, b, y, x0, xls, half != 0);
        __syncthreads();
        const unsigned short* Wh = WF + half * 36864;
#pragma unroll
        for (int kk = 0; kk < 9; ++kk) {
            int dy = kk / 3, dx = kk % 3;
            int xx = p + dx;
#pragma unroll
            for (int ch = 0; ch < 2; ++ch) {
                short8 bfr = read_b(xls, dy, xx, ch * 32 + q4 * 8);
#pragma unroll
                for (int cp = 0; cp < 4; ++cp) {
                    short8 afr = *(const short8*)(Wh + ((kk * 64 + cp * 16 + pl) * 64 + ch * 32 + q4 * 8));
                    acc[cp] = __builtin_amdgcn_mfma_f32_16x16x32_bf16(afr, bfr, acc[cp], 0, 0, 0);
                }
            }
        }
    }
    size_t pglob = (size_t)(b * HWc + y * Wc + x0 + p);
#pragma unroll
    for (int cp = 0; cp < 4; ++cp) {
        int co0 = cp * 16 + q4 * 4;
        f32x4 a2 = *(const f32x4*)(AB + 128 + co0);
        f32x4 b2 = *(const f32x4*)(AB + 192 + co0);
        unsigned short h4[4];
#pragma unroll
        for (int j = 0; j < 4; ++j) h4[j] = f2bf(fmaxf(fmaf(acc[cp][j], a2[j], b2[j]), 0.f));
        uint2 u;
        u.x = (unsigned)h4[0] | ((unsigned)h4[1] << 16);
        u.y = (unsigned)h4[2] | ((unsigned)h4[3] << 16);
        *(uint2*)(hT + pglob * 64 + co0) = u;
    }
}

// ---------------- conv_out: 64->1 ----------------
__global__ __launch_bounds__(256) void convo_m(const unsigned short* __restrict__ hT,
                                               const float* __restrict__ wo,
                                               const float* __restrict__ bo,
                                               float* __restrict__ out) {
    __shared__ float wl[576];
    for (int i = threadIdx.x; i < 576; i += 256) wl[i] = wo[i];
    __syncthreads();
    int p = swz_blk(blockIdx.x, 60) * 256 + threadIdx.x;   // 0..122879
    int xw = p % Wc, rem = p / Wc, y = rem % Hc, b = rem / Hc;
    float acc = bo[0];
#pragma unroll
    for (int kk = 0; kk < 9; ++kk) {
        int iy = y + kk / 3 - 1, ix = xw + kk % 3 - 1;
        if ((unsigned)iy < 96u && (unsigned)ix < 320u) {
            const unsigned short* base = hT + ((size_t)(b * HWc + iy * Wc + ix)) * 64;
#pragma unroll
            for (int g = 0; g < 8; ++g) {
                short8 v = *(const short8*)(base + g * 8);
#pragma unroll
                for (int j = 0; j < 8; ++j)
                    acc = fmaf(bf2f((unsigned short)v[j]), wl[(g * 8 + j) * 9 + kk], acc);
            }
        }
    }
    out[p] = acc;
}

// ---------------- launch ----------------
extern "C" void kernel_launch(void* const* d_in, const int* in_sizes, int n_in,
                              void* d_out, int out_size, void* d_ws, size_t ws_size,
                              hipStream_t stream) {
    const float* feat_rgb   = (const float*)d_in[0];
    const float* feat_depth = (const float*)d_in[1];
    const float* w_off1 = (const float*)d_in[2];
    const float* b_off1 = (const float*)d_in[3];
    const float* g1  = (const float*)d_in[4];
    const float* be1 = (const float*)d_in[5];
    const float* m1  = (const float*)d_in[6];
    const float* v1  = (const float*)d_in[7];
    const float* w_off2 = (const float*)d_in[8];
    const float* b_off2 = (const float*)d_in[9];
    const float* w_def  = (const float*)d_in[10];
    const float* b_def  = (const float*)d_in[11];
    const float* w_f1   = (const float*)d_in[12];
    const float* b_f1   = (const float*)d_in[13];
    const float* g2  = (const float*)d_in[14];
    const float* be2 = (const float*)d_in[15];
    const float* m2  = (const float*)d_in[16];
    const float* v2  = (const float*)d_in[17];
    const float* w_out = (const float*)d_in[18];
    const float* b_out = (const float*)d_in[19];
    (void)in_sizes; (void)n_in; (void)out_size; (void)ws_size;

    char* ws = (char*)d_ws;
    unsigned short* rgbT   = (unsigned short*)(ws + B_RGBT);
    unsigned short* depthT = (unsigned short*)(ws + B_DEPT);
    unsigned short* tT     = (unsigned short*)(ws + B_TT);
    float*          headT  = (float*)(ws + B_HEAD);
    unsigned short* fdreluT = tT;       // reuse (tT dead after conv2)
    unsigned short* hT      = depthT;   // reuse (depthT dead after mdcn)

    prep_w<<<64, 256, 0, stream>>>(w_off1, b_off1, g1, be1, m1, v1,
                                   w_off2, w_def, w_f1, b_f1, g2, be2, m2, v2, ws);
    prep_x<<<(NPIX * 8 + 255) / 256, 256, 0, stream>>>(feat_rgb, feat_depth, rgbT, depthT);
    conv1_m<<<1920, 256, 0, stream>>>(rgbT, ws, tT);
    conv2_m<<<1920, 256, 0, stream>>>(ws, b_off2, headT, tT);
    mdcn_r <<<1920, 256, 0, stream>>>(feat_depth, depthT, headT, ws, b_def, fdreluT);
    convf_m<<<1920, 256, 0, stream>>>(fdreluT, rgbT, ws, hT);
    convo_m<<<480, 256, 0, stream>>>(hT, w_out, b_out, (float*)d_out);
}

// Round 5
// 409.240 us; speedup vs baseline: 10.5623x; 1.3385x over previous
//
#include <hip/hip_runtime.h>
#include <math.h>

// ---------------- problem constants ----------------
constexpr int Bc  = 4;
constexpr int Hc  = 96;
constexpr int Wc  = 320;
constexpr int HWc = Hc * Wc;           // 30720
constexpr int NPIX = Bc * HWc;         // 122880

typedef __attribute__((ext_vector_type(8))) short short8;   // 8 x bf16 fragment
typedef __attribute__((ext_vector_type(4))) float f32x4;    // mfma acc

// ---------------- workspace byte offsets ----------------
constexpr size_t B_W1   = 0;                    // bf16 [9][64co][64ci]   73728 B
constexpr size_t B_W2   = 73728;                // bf16 [9][32co][64ci]   36864 B
constexpr size_t B_WD   = 110592;               // bf16 [9][64o][64c]     73728 B
constexpr size_t B_WF   = 184320;               // bf16 [2][9][64co][64ci]147456 B
constexpr size_t B_AB   = 331776;               // f32 A1,B1,A2,B2        1024 B
constexpr size_t B_RGBT = 332800;               // bf16 [pix][64]         15728640 B
constexpr size_t B_DEPT = 16061440;             // bf16 [pix][64]  (later reused as hT)
constexpr size_t B_TT   = 31790080;             // bf16 [pix][64]  (later reused as fdreluT)
constexpr size_t B_HEAD = 47518720;             // f32  [pix][32]         15728640 B

// ---------------- helpers ----------------
static __device__ __forceinline__ unsigned short f2bf(float f) {
    unsigned u = __builtin_bit_cast(unsigned, f);
    u = (u + 0x7fffu + ((u >> 16) & 1u)) >> 16;   // RNE
    return (unsigned short)u;
}
static __device__ __forceinline__ float bf2f(unsigned short h) {
    unsigned u = ((unsigned)h) << 16;
    return __builtin_bit_cast(float, u);
}
// XCD-aware block swizzle: grid divisible by 8; each XCD gets contiguous chunk.
static __device__ __forceinline__ int swz_blk(int bid, int chunk) {
    return (bid & 7) * chunk + (bid >> 3);
}

// ---------------- prep: weights + BN folds ----------------
__global__ void prep_w(const float* __restrict__ w1, const float* __restrict__ b1,
                       const float* __restrict__ g1, const float* __restrict__ be1,
                       const float* __restrict__ m1, const float* __restrict__ v1,
                       const float* __restrict__ w2,
                       const float* __restrict__ wd,
                       const float* __restrict__ wf, const float* __restrict__ bf1,
                       const float* __restrict__ g2, const float* __restrict__ be2,
                       const float* __restrict__ m2, const float* __restrict__ v2,
                       char* __restrict__ ws) {
    int tid = blockIdx.x * blockDim.x + threadIdx.x;
    int stride = gridDim.x * blockDim.x;
    unsigned short* W1 = (unsigned short*)(ws + B_W1);
    unsigned short* W2 = (unsigned short*)(ws + B_W2);
    unsigned short* WD = (unsigned short*)(ws + B_WD);
    unsigned short* WF = (unsigned short*)(ws + B_WF);
    float* AB = (float*)(ws + B_AB);
    for (int i = tid; i < 36864; i += stride) {         // W1p [kk][co][ci]
        int ci = i & 63, co = (i >> 6) & 63, kk = i >> 12;
        W1[i] = f2bf(w1[(co * 64 + ci) * 9 + kk]);
    }
    for (int i = tid; i < 18432; i += stride) {         // W2p [kk][32co][ci]
        int ci = i & 63, co = (i >> 6) & 31, kk = i >> 11;
        W2[i] = (co < 27) ? f2bf(w2[(co * 64 + ci) * 9 + kk]) : (unsigned short)0;
    }
    for (int i = tid; i < 36864; i += stride) {         // Wdp [kk][o][c]
        int c = i & 63, o = (i >> 6) & 63, kk = i >> 12;
        WD[i] = f2bf(wd[(o * 64 + c) * 9 + kk]);
    }
    for (int i = tid; i < 73728; i += stride) {         // Wfp [half][kk][co][ci]
        int ci = i & 63, co = (i >> 6) & 63, r = i >> 12;
        int kk = r % 9, h = r / 9;
        WF[i] = f2bf(wf[(co * 128 + h * 64 + ci) * 9 + kk]);
    }
    if (tid < 64) {
        float s1 = g1[tid] / sqrtf(v1[tid] + 1e-5f);
        AB[tid]        = s1;
        AB[64 + tid]   = b1[tid] * s1 + be1[tid] - m1[tid] * s1;
        float s2 = g2[tid] / sqrtf(v2[tid] + 1e-5f);
        AB[128 + tid]  = s2;
        AB[192 + tid]  = bf1[tid] * s2 + be2[tid] - m2[tid] * s2;
    }
}

// ---------------- prep: transpose inputs to pixel-major bf16 ----------------
__global__ __launch_bounds__(256) void prep_x(const float* __restrict__ rgb,
                                              const float* __restrict__ dep,
                                              unsigned short* __restrict__ rgbT,
                                              unsigned short* __restrict__ depT) {
    int i = blockIdx.x * 256 + threadIdx.x;     // over NPIX*8
    if (i >= NPIX * 8) return;
    int g = i & 7;                 // ci-group (8 channels)
    int pg = i >> 3;               // flat pixel 0..122879
    int b = pg / HWc, p = pg % HWc;
    size_t sb = (size_t)b * 64 * HWc + p + (size_t)(g * 8) * HWc;
    unsigned short r8[8], d8[8];
#pragma unroll
    for (int j = 0; j < 8; ++j) {
        r8[j] = f2bf(rgb[sb + (size_t)j * HWc]);
        d8[j] = f2bf(dep[sb + (size_t)j * HWc]);
    }
    *(short8*)(rgbT + (size_t)pg * 64 + g * 8) = *(short8*)r8;
    *(short8*)(depT + (size_t)pg * 64 + g * 8) = *(short8*)d8;
}

// ---------------- LDS staging: 6-row halo tile ----------------
// LDS layout: [6 rows][66 xx][64 ci] bf16, byte addr ^= ((xx&7)<<4)
static __device__ __forceinline__ void stage6(const unsigned short* __restrict__ src,
                                              int b, int y0, int x0,
                                              unsigned short* lds, bool do_relu) {
#pragma unroll
    for (int it = 0; it < 13; ++it) {
        int i = threadIdx.x + it * 256;
        if (i < 3168) {                       // 6*66*8
            int g = i & 7;
            int xx = (i >> 3) % 66;
            int row = (i >> 3) / 66;
            int y = y0 - 1 + row, x = x0 - 1 + xx;
            short8 v = (short8)0;
            if ((unsigned)y < 96u && (unsigned)x < 320u) {
                v = *(const short8*)(src + ((size_t)(b * HWc + y * Wc + x)) * 64 + g * 8);
            }
            if (do_relu) {
#pragma unroll
                for (int j = 0; j < 8; ++j) {
                    short s = v[j];
                    v[j] = (s & (short)0x8000) ? (short)0 : s;
                }
            }
            int byte = ((row * 66 + xx) * 64 + g * 8) * 2;
            byte ^= ((xx & 7) << 4);
            *(short8*)((char*)lds + byte) = v;
        }
    }
}

static __device__ __forceinline__ short8 read_b6(const unsigned short* lds, int row, int xx, int cofs) {
    int byte = ((row * 66 + xx) * 64 + cofs) * 2;
    byte ^= ((xx & 7) << 4);
    return *(const short8*)((const char*)lds + byte);
}

// ---------------- conv1: 64->64 + BN, rgbT -> tT  (4-row blocks) ----------------
__global__ __launch_bounds__(256) void conv1_m(const unsigned short* __restrict__ rgbT,
                                               const char* __restrict__ ws,
                                               unsigned short* __restrict__ tT) {
    __shared__ __align__(16) unsigned short xls[6 * 66 * 64];
    const unsigned short* W1 = (const unsigned short*)(ws + B_W1);
    const float* AB = (const float*)(ws + B_AB);
    int blk = swz_blk(blockIdx.x, 60);        // 480 blocks
    int xt = blk % 5, yt = (blk / 5) % 24, b = blk / 120;
    int x0 = xt * 64, y0 = yt * 4;
    stage6(rgbT, b, y0, x0, xls, false);
    __syncthreads();
    int lane = threadIdx.x & 63, w = threadIdx.x >> 6;
    int pl = lane & 15, q4 = lane >> 4;
    int p = w * 16 + pl;
    f32x4 acc[4][4];                          // [row][cp]
#pragma unroll
    for (int r = 0; r < 4; ++r)
#pragma unroll
        for (int cp = 0; cp < 4; ++cp) acc[r][cp] = (f32x4)0.f;
#pragma unroll
    for (int kk = 0; kk < 9; ++kk) {
        int dy = kk / 3, dx = kk % 3;
        int xx = p + dx;
#pragma unroll
        for (int ch = 0; ch < 2; ++ch) {
            short8 bfr[4];
#pragma unroll
            for (int r = 0; r < 4; ++r) bfr[r] = read_b6(xls, dy + r, xx, ch * 32 + q4 * 8);
#pragma unroll
            for (int cp = 0; cp < 4; ++cp) {
                short8 afr = *(const short8*)(W1 + ((kk * 64 + cp * 16 + pl) * 64 + ch * 32 + q4 * 8));
#pragma unroll
                for (int r = 0; r < 4; ++r)
                    acc[r][cp] = __builtin_amdgcn_mfma_f32_16x16x32_bf16(afr, bfr[r], acc[r][cp], 0, 0, 0);
            }
        }
    }
#pragma unroll
    for (int r = 0; r < 4; ++r) {
        size_t pglob = (size_t)(b * HWc + (y0 + r) * Wc + x0 + p);
#pragma unroll
        for (int cp = 0; cp < 4; ++cp) {
            int co0 = cp * 16 + q4 * 4;
            f32x4 a1 = *(const f32x4*)(AB + co0);
            f32x4 b1 = *(const f32x4*)(AB + 64 + co0);
            unsigned short h4[4];
#pragma unroll
            for (int j = 0; j < 4; ++j) h4[j] = f2bf(fmaf(acc[r][cp][j], a1[j], b1[j]));
            uint2 u;
            u.x = (unsigned)h4[0] | ((unsigned)h4[1] << 16);
            u.y = (unsigned)h4[2] | ((unsigned)h4[3] << 16);
            *(uint2*)(tT + pglob * 64 + co0) = u;
        }
    }
}

// ---------------- conv2: 64->27(pad32), tT -> headT (f32)  (4-row blocks) ----------------
__global__ __launch_bounds__(256) void conv2_m(const char* __restrict__ ws,
                                               const float* __restrict__ b2,
                                               float* __restrict__ headT,
                                               const unsigned short* __restrict__ tT) {
    __shared__ __align__(16) unsigned short xls[6 * 66 * 64];
    const unsigned short* W2 = (const unsigned short*)(ws + B_W2);
    int blk = swz_blk(blockIdx.x, 60);
    int xt = blk % 5, yt = (blk / 5) % 24, b = blk / 120;
    int x0 = xt * 64, y0 = yt * 4;
    stage6(tT, b, y0, x0, xls, false);
    __syncthreads();
    int lane = threadIdx.x & 63, w = threadIdx.x >> 6;
    int pl = lane & 15, q4 = lane >> 4;
    int p = w * 16 + pl;
    f32x4 acc[4][2];
#pragma unroll
    for (int r = 0; r < 4; ++r) { acc[r][0] = (f32x4)0.f; acc[r][1] = (f32x4)0.f; }
#pragma unroll
    for (int kk = 0; kk < 9; ++kk) {
        int dy = kk / 3, dx = kk % 3;
        int xx = p + dx;
#pragma unroll
        for (int ch = 0; ch < 2; ++ch) {
            short8 bfr[4];
#pragma unroll
            for (int r = 0; r < 4; ++r) bfr[r] = read_b6(xls, dy + r, xx, ch * 32 + q4 * 8);
#pragma unroll
            for (int cp = 0; cp < 2; ++cp) {
                short8 afr = *(const short8*)(W2 + ((kk * 32 + cp * 16 + pl) * 64 + ch * 32 + q4 * 8));
#pragma unroll
                for (int r = 0; r < 4; ++r)
                    acc[r][cp] = __builtin_amdgcn_mfma_f32_16x16x32_bf16(afr, bfr[r], acc[r][cp], 0, 0, 0);
            }
        }
    }
#pragma unroll
    for (int r = 0; r < 4; ++r) {
        size_t pglob = (size_t)(b * HWc + (y0 + r) * Wc + x0 + p);
#pragma unroll
        for (int cp = 0; cp < 2; ++cp) {
            int co0 = cp * 16 + q4 * 4;
            f32x4 rr;
#pragma unroll
            for (int j = 0; j < 4; ++j) {
                float bias = (co0 + j < 27) ? b2[co0 + j] : 0.f;
                rr[j] = acc[r][cp][j] + bias;
            }
            *(f32x4*)(headT + pglob * 32 + co0) = rr;
        }
    }
}

// ---- mdcn: register-direct bilinear, depth-2 software pipeline, no LDS ----
__global__ __launch_bounds__(256) void mdcn_r(const float* __restrict__ feat_depth,
                                              const unsigned short* __restrict__ depthT,
                                              const float* __restrict__ headT,
                                              const char* __restrict__ ws,
                                              const float* __restrict__ bd,
                                              unsigned short* __restrict__ fdreluT) {
    const unsigned short* WD = (const unsigned short*)(ws + B_WD);
    int blk = swz_blk(blockIdx.x, 240);
    int xt = blk % 5, y = (blk / 5) % 96, b = blk / 480;
    int x0 = xt * 64;
    int lane = threadIdx.x & 63, w = threadIdx.x >> 6;
    int pl = lane & 15, q4 = lane >> 4;
    int p = w * 16 + pl;
    int px = x0 + p;
    size_t pglob = (size_t)(b * HWc + y * Wc + px);
    size_t dbase = (size_t)b * HWc * 64;
    const float* hd = headT + pglob * 32;
    float hv[28];
#pragma unroll
    for (int i = 0; i < 7; ++i) {
        f32x4 t = *(const f32x4*)(hd + i * 4);
        hv[i * 4 + 0] = t[0]; hv[i * 4 + 1] = t[1];
        hv[i * 4 + 2] = t[2]; hv[i * 4 + 3] = t[3];
    }
    f32x4 acc[4];
#pragma unroll
    for (int cp = 0; cp < 4; ++cp) acc[cp] = (f32x4)0.f;

    int   o_[2][4];        // ping-pong corner element-offsets
    float w_[2][4];        // ping-pong bilinear*mask weights
    short8 f_[2][8];       // ping-pong corner data (corner*2 + ch)

#define MPARAMS(KK, S) {                                                      \
    float dyv = hv[2*(KK)], dxv = hv[2*(KK)+1], sm = hv[18+(KK)];             \
    float m = 1.f / (1.f + __expf(-sm));                                      \
    float py  = (float)(y + (KK)/3 - 1) + dyv;                                \
    float pxf = (float)(px + (KK)%3 - 1) + dxv;                               \
    float y0f = floorf(py), x0f = floorf(pxf);                                \
    float wy = py - y0f, wx = pxf - x0f;                                      \
    int iy0 = (int)y0f, ix0 = (int)x0f;                                       \
    bool vy0 = (unsigned)iy0 < 96u, vy1 = (unsigned)(iy0+1) < 96u;            \
    bool vx0 = (unsigned)ix0 < 320u, vx1 = (unsigned)(ix0+1) < 320u;          \
    int cy0 = min(max(iy0,0),95),  cy1 = min(max(iy0+1,0),95);                \
    int cx0 = min(max(ix0,0),319), cx1 = min(max(ix0+1,0),319);               \
    w_[S][0] = (vy0 && vx0) ? (1.f-wy)*(1.f-wx)*m : 0.f;                      \
    w_[S][1] = (vy0 && vx1) ? (1.f-wy)*wx*m : 0.f;                            \
    w_[S][2] = (vy1 && vx0) ? wy*(1.f-wx)*m : 0.f;                            \
    w_[S][3] = (vy1 && vx1) ? wy*wx*m : 0.f;                                  \
    o_[S][0] = cy0*Wc+cx0; o_[S][1] = cy0*Wc+cx1;                             \
    o_[S][2] = cy1*Wc+cx0; o_[S][3] = cy1*Wc+cx1; }

#define MISSUE(S) {                                                           \
    const unsigned short* bp = depthT + dbase + q4 * 8;                       \
    _Pragma("unroll")                                                         \
    for (int c = 0; c < 4; ++c) {                                             \
        const unsigned short* rp = bp + (size_t)o_[S][c] * 64;                \
        f_[S][c*2+0] = *(const short8*)(rp);                                  \
        f_[S][c*2+1] = *(const short8*)(rp + 32);                             \
    } }

    MPARAMS(0, 0)
    MISSUE(0)
#pragma unroll
    for (int kk = 0; kk < 9; ++kk) {
        int cur = kk & 1, nxt = cur ^ 1;
        if (kk < 8) {           // issue next batch before consuming current
            MPARAMS(kk + 1, nxt)
            MISSUE(nxt)
        }
#pragma unroll
        for (int ch = 0; ch < 2; ++ch) {
            unsigned short vv[8];
#pragma unroll
            for (int j = 0; j < 8; ++j) {
                float v = w_[cur][0] * bf2f((unsigned short)f_[cur][0*2+ch][j])
                        + w_[cur][1] * bf2f((unsigned short)f_[cur][1*2+ch][j])
                        + w_[cur][2] * bf2f((unsigned short)f_[cur][2*2+ch][j])
                        + w_[cur][3] * bf2f((unsigned short)f_[cur][3*2+ch][j]);
                vv[j] = f2bf(v);
            }
            short8 bfr = *(short8*)vv;
#pragma unroll
            for (int cp = 0; cp < 4; ++cp) {
                short8 afr = *(const short8*)(WD + ((kk * 64 + cp * 16 + pl) * 64 + ch * 32 + q4 * 8));
                acc[cp] = __builtin_amdgcn_mfma_f32_16x16x32_bf16(afr, bfr, acc[cp], 0, 0, 0);
            }
        }
    }
#undef MPARAMS
#undef MISSUE
    // epilogue: fdrelu = relu(acc + bd + feat_depth) -> bf16 [pix][64]
    int pix = y * Wc + px;
#pragma unroll
    for (int cp = 0; cp < 4; ++cp) {
        int co0 = cp * 16 + q4 * 4;
        f32x4 bdv = *(const f32x4*)(bd + co0);
        unsigned short h4[4];
#pragma unroll
        for (int j = 0; j < 4; ++j) {
            float r = acc[cp][j] + bdv[j] + feat_depth[((size_t)b * 64 + co0 + j) * HWc + pix];
            h4[j] = f2bf(fmaxf(r, 0.f));
        }
        uint2 u;
        u.x = (unsigned)h4[0] | ((unsigned)h4[1] << 16);
        u.y = (unsigned)h4[2] | ((unsigned)h4[3] << 16);
        *(uint2*)(fdreluT + ((size_t)(b * HWc) + pix) * 64 + co0) = u;
    }
}

// ---------------- convf: 128->64 + BN + relu -> hT  (4-row blocks) ----------------
__global__ __launch_bounds__(256) void convf_m(const unsigned short* __restrict__ fdreluT,
                                               const unsigned short* __restrict__ rgbT,
                                               const char* __restrict__ ws,
                                               unsigned short* __restrict__ hT) {
    __shared__ __align__(16) unsigned short xls[6 * 66 * 64];
    const unsigned short* WF = (const unsigned short*)(ws + B_WF);
    const float* AB = (const float*)(ws + B_AB);
    int blk = swz_blk(blockIdx.x, 60);
    int xt = blk % 5, yt = (blk / 5) % 24, b = blk / 120;
    int x0 = xt * 64, y0 = yt * 4;
    int lane = threadIdx.x & 63, w = threadIdx.x >> 6;
    int pl = lane & 15, q4 = lane >> 4;
    int p = w * 16 + pl;
    f32x4 acc[4][4];
#pragma unroll
    for (int r = 0; r < 4; ++r)
#pragma unroll
        for (int cp = 0; cp < 4; ++cp) acc[r][cp] = (f32x4)0.f;
#pragma unroll
    for (int half = 0; half < 2; ++half) {
        if (half) __syncthreads();
        stage6(half ? rgbT : fdreluT, b, y0, x0, xls, half != 0);
        __syncthreads();
        const unsigned short* Wh = WF + half * 36864;
#pragma unroll
        for (int kk = 0; kk < 9; ++kk) {
            int dy = kk / 3, dx = kk % 3;
            int xx = p + dx;
#pragma unroll
            for (int ch = 0; ch < 2; ++ch) {
                short8 bfr[4];
#pragma unroll
                for (int r = 0; r < 4; ++r) bfr[r] = read_b6(xls, dy + r, xx, ch * 32 + q4 * 8);
#pragma unroll
                for (int cp = 0; cp < 4; ++cp) {
                    short8 afr = *(const short8*)(Wh + ((kk * 64 + cp * 16 + pl) * 64 + ch * 32 + q4 * 8));
#pragma unroll
                    for (int r = 0; r < 4; ++r)
                        acc[r][cp] = __builtin_amdgcn_mfma_f32_16x16x32_bf16(afr, bfr[r], acc[r][cp], 0, 0, 0);
                }
            }
        }
    }
#pragma unroll
    for (int r = 0; r < 4; ++r) {
        size_t pglob = (size_t)(b * HWc + (y0 + r) * Wc + x0 + p);
#pragma unroll
        for (int cp = 0; cp < 4; ++cp) {
            int co0 = cp * 16 + q4 * 4;
            f32x4 a2 = *(const f32x4*)(AB + 128 + co0);
            f32x4 b2 = *(const f32x4*)(AB + 192 + co0);
            unsigned short h4[4];
#pragma unroll
            for (int j = 0; j < 4; ++j) h4[j] = f2bf(fmaxf(fmaf(acc[r][cp][j], a2[j], b2[j]), 0.f));
            uint2 u;
            u.x = (unsigned)h4[0] | ((unsigned)h4[1] << 16);
            u.y = (unsigned)h4[2] | ((unsigned)h4[3] << 16);
            *(uint2*)(hT + pglob * 64 + co0) = u;
        }
    }
}

// ---------------- conv_out: 64->1 ----------------
__global__ __launch_bounds__(256) void convo_m(const unsigned short* __restrict__ hT,
                                               const float* __restrict__ wo,
                                               const float* __restrict__ bo,
                                               float* __restrict__ out) {
    __shared__ float wl[576];
    for (int i = threadIdx.x; i < 576; i += 256) wl[i] = wo[i];
    __syncthreads();
    int p = swz_blk(blockIdx.x, 60) * 256 + threadIdx.x;   // 0..122879
    int xw = p % Wc, rem = p / Wc, y = rem % Hc, b = rem / Hc;
    float acc = bo[0];
#pragma unroll
    for (int kk = 0; kk < 9; ++kk) {
        int iy = y + kk / 3 - 1, ix = xw + kk % 3 - 1;
        if ((unsigned)iy < 96u && (unsigned)ix < 320u) {
            const unsigned short* base = hT + ((size_t)(b * HWc + iy * Wc + ix)) * 64;
#pragma unroll
            for (int g = 0; g < 8; ++g) {
                short8 v = *(const short8*)(base + g * 8);
#pragma unroll
                for (int j = 0; j < 8; ++j)
                    acc = fmaf(bf2f((unsigned short)v[j]), wl[(g * 8 + j) * 9 + kk], acc);
            }
        }
    }
    out[p] = acc;
}

// ---------------- launch ----------------
extern "C" void kernel_launch(void* const* d_in, const int* in_sizes, int n_in,
                              void* d_out, int out_size, void* d_ws, size_t ws_size,
                              hipStream_t stream) {
    const float* feat_rgb   = (const float*)d_in[0];
    const float* feat_depth = (const float*)d_in[1];
    const float* w_off1 = (const float*)d_in[2];
    const float* b_off1 = (const float*)d_in[3];
    const float* g1  = (const float*)d_in[4];
    const float* be1 = (const float*)d_in[5];
    const float* m1  = (const float*)d_in[6];
    const float* v1  = (const float*)d_in[7];
    const float* w_off2 = (const float*)d_in[8];
    const float* b_off2 = (const float*)d_in[9];
    const float* w_def  = (const float*)d_in[10];
    const float* b_def  = (const float*)d_in[11];
    const float* w_f1   = (const float*)d_in[12];
    const float* b_f1   = (const float*)d_in[13];
    const float* g2  = (const float*)d_in[14];
    const float* be2 = (const float*)d_in[15];
    const float* m2  = (const float*)d_in[16];
    const float* v2  = (const float*)d_in[17];
    const float* w_out = (const float*)d_in[18];
    const float* b_out = (const float*)d_in[19];
    (void)in_sizes; (void)n_in; (void)out_size; (void)ws_size;

    char* ws = (char*)d_ws;
    unsigned short* rgbT   = (unsigned short*)(ws + B_RGBT);
    unsigned short* depthT = (unsigned short*)(ws + B_DEPT);
    unsigned short* tT     = (unsigned short*)(ws + B_TT);
    float*          headT  = (float*)(ws + B_HEAD);
    unsigned short* fdreluT = tT;       // reuse (tT dead after conv2)
    unsigned short* hT      = depthT;   // reuse (depthT dead after mdcn)

    prep_w<<<64, 256, 0, stream>>>(w_off1, b_off1, g1, be1, m1, v1,
                                   w_off2, w_def, w_f1, b_f1, g2, be2, m2, v2, ws);
    prep_x<<<(NPIX * 8 + 255) / 256, 256, 0, stream>>>(feat_rgb, feat_depth, rgbT, depthT);
    conv1_m<<<480, 256, 0, stream>>>(rgbT, ws, tT);
    conv2_m<<<480, 256, 0, stream>>>(ws, b_off2, headT, tT);
    mdcn_r <<<1920, 256, 0, stream>>>(feat_depth, depthT, headT, ws, b_def, fdreluT);
    convf_m<<<480, 256, 0, stream>>>(fdreluT, rgbT, ws, hT);
    convo_m<<<480, 256, 0, stream>>>(hT, w_out, b_out, (float*)d_out);
}

// Round 7
// 396.399 us; speedup vs baseline: 10.9044x; 1.0324x over previous
//
#include <hip/hip_runtime.h>
#include <math.h>

// ---------------- problem constants ----------------
constexpr int Bc  = 4;
constexpr int Hc  = 96;
constexpr int Wc  = 320;
constexpr int HWc = Hc * Wc;           // 30720
constexpr int NPIX = Bc * HWc;         // 122880

typedef __attribute__((ext_vector_type(8))) short short8;   // 8 x bf16 fragment
typedef __attribute__((ext_vector_type(4))) float f32x4;    // mfma acc

// ---------------- workspace byte offsets ----------------
constexpr size_t B_W1   = 0;                    // bf16 [9][64co][64ci]   73728 B
constexpr size_t B_W2   = 73728;                // bf16 [9][32co][64ci]   36864 B
constexpr size_t B_WD   = 110592;               // bf16 [9][64o][64c]     73728 B
constexpr size_t B_WF   = 184320;               // bf16 [2][9][64co][64ci]147456 B
constexpr size_t B_AB   = 331776;               // f32 A1,B1,A2,B2        1024 B
constexpr size_t B_RGBT = 332800;               // bf16 [pix][64]         15728640 B
constexpr size_t B_DEPT = 16061440;             // bf16 [pix][64]  (later reused as hT)
constexpr size_t B_TT   = 31790080;             // bf16 [pix][64]  (later reused as fdreluT)
constexpr size_t B_HEAD = 47518720;             // f32  [pix][32]         15728640 B

// ---------------- helpers ----------------
static __device__ __forceinline__ unsigned short f2bf(float f) {
    unsigned u = __builtin_bit_cast(unsigned, f);
    u = (u + 0x7fffu + ((u >> 16) & 1u)) >> 16;   // RNE
    return (unsigned short)u;
}
static __device__ __forceinline__ float bf2f(unsigned short h) {
    unsigned u = ((unsigned)h) << 16;
    return __builtin_bit_cast(float, u);
}
// XCD-aware block swizzle: grid divisible by 8; each XCD gets contiguous chunk.
static __device__ __forceinline__ int swz_blk(int bid, int chunk) {
    return (bid & 7) * chunk + (bid >> 3);
}

// ---------------- prep: weights + BN folds ----------------
__global__ void prep_w(const float* __restrict__ w1, const float* __restrict__ b1,
                       const float* __restrict__ g1, const float* __restrict__ be1,
                       const float* __restrict__ m1, const float* __restrict__ v1,
                       const float* __restrict__ w2,
                       const float* __restrict__ wd,
                       const float* __restrict__ wf, const float* __restrict__ bf1,
                       const float* __restrict__ g2, const float* __restrict__ be2,
                       const float* __restrict__ m2, const float* __restrict__ v2,
                       char* __restrict__ ws) {
    int tid = blockIdx.x * blockDim.x + threadIdx.x;
    int stride = gridDim.x * blockDim.x;
    unsigned short* W1 = (unsigned short*)(ws + B_W1);
    unsigned short* W2 = (unsigned short*)(ws + B_W2);
    unsigned short* WD = (unsigned short*)(ws + B_WD);
    unsigned short* WF = (unsigned short*)(ws + B_WF);
    float* AB = (float*)(ws + B_AB);
    for (int i = tid; i < 36864; i += stride) {         // W1p [kk][co][ci]
        int ci = i & 63, co = (i >> 6) & 63, kk = i >> 12;
        W1[i] = f2bf(w1[(co * 64 + ci) * 9 + kk]);
    }
    for (int i = tid; i < 18432; i += stride) {         // W2p [kk][32co][ci]
        int ci = i & 63, co = (i >> 6) & 31, kk = i >> 11;
        W2[i] = (co < 27) ? f2bf(w2[(co * 64 + ci) * 9 + kk]) : (unsigned short)0;
    }
    for (int i = tid; i < 36864; i += stride) {         // Wdp [kk][o][c]
        int c = i & 63, o = (i >> 6) & 63, kk = i >> 12;
        WD[i] = f2bf(wd[(o * 64 + c) * 9 + kk]);
    }
    for (int i = tid; i < 73728; i += stride) {         // Wfp [half][kk][co][ci]
        int ci = i & 63, co = (i >> 6) & 63, r = i >> 12;
        int kk = r % 9, h = r / 9;
        WF[i] = f2bf(wf[(co * 128 + h * 64 + ci) * 9 + kk]);
    }
    if (tid < 64) {
        float s1 = g1[tid] / sqrtf(v1[tid] + 1e-5f);
        AB[tid]        = s1;
        AB[64 + tid]   = b1[tid] * s1 + be1[tid] - m1[tid] * s1;
        float s2 = g2[tid] / sqrtf(v2[tid] + 1e-5f);
        AB[128 + tid]  = s2;
        AB[192 + tid]  = bf1[tid] * s2 + be2[tid] - m2[tid] * s2;
    }
}

// ---------------- prep: transpose inputs to pixel-major bf16 ----------------
__global__ __launch_bounds__(256) void prep_x(const float* __restrict__ rgb,
                                              const float* __restrict__ dep,
                                              unsigned short* __restrict__ rgbT,
                                              unsigned short* __restrict__ depT) {
    int i = blockIdx.x * 256 + threadIdx.x;     // over NPIX*8
    if (i >= NPIX * 8) return;
    int g = i & 7;                 // ci-group (8 channels)
    int pg = i >> 3;               // flat pixel 0..122879
    int b = pg / HWc, p = pg % HWc;
    size_t sb = (size_t)b * 64 * HWc + p + (size_t)(g * 8) * HWc;
    unsigned short r8[8], d8[8];
#pragma unroll
    for (int j = 0; j < 8; ++j) {
        r8[j] = f2bf(rgb[sb + (size_t)j * HWc]);
        d8[j] = f2bf(dep[sb + (size_t)j * HWc]);
    }
    *(short8*)(rgbT + (size_t)pg * 64 + g * 8) = *(short8*)r8;
    *(short8*)(depT + (size_t)pg * 64 + g * 8) = *(short8*)d8;
}

// ---------------- LDS staging: 6-row halo tile (convs) ----------------
// LDS layout: [6 rows][66 xx][64 ci] bf16, byte addr ^= ((xx&7)<<4)
static __device__ __forceinline__ void stage6(const unsigned short* __restrict__ src,
                                              int b, int y0, int x0,
                                              unsigned short* lds, bool do_relu) {
#pragma unroll
    for (int it = 0; it < 13; ++it) {
        int i = threadIdx.x + it * 256;
        if (i < 3168) {                       // 6*66*8
            int g = i & 7;
            int xx = (i >> 3) % 66;
            int row = (i >> 3) / 66;
            int y = y0 - 1 + row, x = x0 - 1 + xx;
            short8 v = (short8)0;
            if ((unsigned)y < 96u && (unsigned)x < 320u) {
                v = *(const short8*)(src + ((size_t)(b * HWc + y * Wc + x)) * 64 + g * 8);
            }
            if (do_relu) {
#pragma unroll
                for (int j = 0; j < 8; ++j) {
                    short s = v[j];
                    v[j] = (s & (short)0x8000) ? (short)0 : s;
                }
            }
            int byte = ((row * 66 + xx) * 64 + g * 8) * 2;
            byte ^= ((xx & 7) << 4);
            *(short8*)((char*)lds + byte) = v;
        }
    }
}

static __device__ __forceinline__ short8 read_b6(const unsigned short* lds, int row, int xx, int cofs) {
    int byte = ((row * 66 + xx) * 64 + cofs) * 2;
    byte ^= ((xx & 7) << 4);
    return *(const short8*)((const char*)lds + byte);
}

// ---------------- conv1: 64->64 + BN, rgbT -> tT  (4-row blocks) ----------------
__global__ __launch_bounds__(256) void conv1_m(const unsigned short* __restrict__ rgbT,
                                               const char* __restrict__ ws,
                                               unsigned short* __restrict__ tT) {
    __shared__ __align__(16) unsigned short xls[6 * 66 * 64];
    const unsigned short* W1 = (const unsigned short*)(ws + B_W1);
    const float* AB = (const float*)(ws + B_AB);
    int blk = swz_blk(blockIdx.x, 60);        // 480 blocks
    int xt = blk % 5, yt = (blk / 5) % 24, b = blk / 120;
    int x0 = xt * 64, y0 = yt * 4;
    stage6(rgbT, b, y0, x0, xls, false);
    __syncthreads();
    int lane = threadIdx.x & 63, w = threadIdx.x >> 6;
    int pl = lane & 15, q4 = lane >> 4;
    int p = w * 16 + pl;
    f32x4 acc[4][4];                          // [row][cp]
#pragma unroll
    for (int r = 0; r < 4; ++r)
#pragma unroll
        for (int cp = 0; cp < 4; ++cp) acc[r][cp] = (f32x4)0.f;
#pragma unroll
    for (int kk = 0; kk < 9; ++kk) {
        int dy = kk / 3, dx = kk % 3;
        int xx = p + dx;
#pragma unroll
        for (int ch = 0; ch < 2; ++ch) {
            short8 bfr[4];
#pragma unroll
            for (int r = 0; r < 4; ++r) bfr[r] = read_b6(xls, dy + r, xx, ch * 32 + q4 * 8);
#pragma unroll
            for (int cp = 0; cp < 4; ++cp) {
                short8 afr = *(const short8*)(W1 + ((kk * 64 + cp * 16 + pl) * 64 + ch * 32 + q4 * 8));
#pragma unroll
                for (int r = 0; r < 4; ++r)
                    acc[r][cp] = __builtin_amdgcn_mfma_f32_16x16x32_bf16(afr, bfr[r], acc[r][cp], 0, 0, 0);
            }
        }
    }
#pragma unroll
    for (int r = 0; r < 4; ++r) {
        size_t pglob = (size_t)(b * HWc + (y0 + r) * Wc + x0 + p);
#pragma unroll
        for (int cp = 0; cp < 4; ++cp) {
            int co0 = cp * 16 + q4 * 4;
            f32x4 a1 = *(const f32x4*)(AB + co0);
            f32x4 b1 = *(const f32x4*)(AB + 64 + co0);
            unsigned short h4[4];
#pragma unroll
            for (int j = 0; j < 4; ++j) h4[j] = f2bf(fmaf(acc[r][cp][j], a1[j], b1[j]));
            uint2 u;
            u.x = (unsigned)h4[0] | ((unsigned)h4[1] << 16);
            u.y = (unsigned)h4[2] | ((unsigned)h4[3] << 16);
            *(uint2*)(tT + pglob * 64 + co0) = u;
        }
    }
}

// ---------------- conv2: 64->27(pad32), tT -> headT (f32)  (4-row blocks) ----------------
__global__ __launch_bounds__(256) void conv2_m(const char* __restrict__ ws,
                                               const float* __restrict__ b2,
                                               float* __restrict__ headT,
                                               const unsigned short* __restrict__ tT) {
    __shared__ __align__(16) unsigned short xls[6 * 66 * 64];
    const unsigned short* W2 = (const unsigned short*)(ws + B_W2);
    int blk = swz_blk(blockIdx.x, 60);
    int xt = blk % 5, yt = (blk / 5) % 24, b = blk / 120;
    int x0 = xt * 64, y0 = yt * 4;
    stage6(tT, b, y0, x0, xls, false);
    __syncthreads();
    int lane = threadIdx.x & 63, w = threadIdx.x >> 6;
    int pl = lane & 15, q4 = lane >> 4;
    int p = w * 16 + pl;
    f32x4 acc[4][2];
#pragma unroll
    for (int r = 0; r < 4; ++r) { acc[r][0] = (f32x4)0.f; acc[r][1] = (f32x4)0.f; }
#pragma unroll
    for (int kk = 0; kk < 9; ++kk) {
        int dy = kk / 3, dx = kk % 3;
        int xx = p + dx;
#pragma unroll
        for (int ch = 0; ch < 2; ++ch) {
            short8 bfr[4];
#pragma unroll
            for (int r = 0; r < 4; ++r) bfr[r] = read_b6(xls, dy + r, xx, ch * 32 + q4 * 8);
#pragma unroll
            for (int cp = 0; cp < 2; ++cp) {
                short8 afr = *(const short8*)(W2 + ((kk * 32 + cp * 16 + pl) * 64 + ch * 32 + q4 * 8));
#pragma unroll
                for (int r = 0; r < 4; ++r)
                    acc[r][cp] = __builtin_amdgcn_mfma_f32_16x16x32_bf16(afr, bfr[r], acc[r][cp], 0, 0, 0);
            }
        }
    }
#pragma unroll
    for (int r = 0; r < 4; ++r) {
        size_t pglob = (size_t)(b * HWc + (y0 + r) * Wc + x0 + p);
#pragma unroll
        for (int cp = 0; cp < 2; ++cp) {
            int co0 = cp * 16 + q4 * 4;
            f32x4 rr;
#pragma unroll
            for (int j = 0; j < 4; ++j) {
                float bias = (co0 + j < 27) ? b2[co0 + j] : 0.f;
                rr[j] = acc[r][cp][j] + bias;
            }
            *(f32x4*)(headT + pglob * 32 + co0) = rr;
        }
    }
}

// ---- mdcn: LDS-windowed gather (global fallback) + 576-K GEMM -> fdreluT ----
// Window per block: rows [y-5,y+5] x cols [x0-5,x0+68], half channels per pass.
// LDS [11][74][32ch] bf16 = 52096 B; byte = ((r*74+c)*64 + sub*16) ^ ((c&6)<<3)
__global__ __launch_bounds__(256) void mdcn_l(const unsigned short* __restrict__ depthT,
                                              const float* __restrict__ headT,
                                              const char* __restrict__ ws,
                                              const float* __restrict__ bd,
                                              unsigned short* __restrict__ fdreluT) {
    __shared__ __align__(16) unsigned short vls[26048];   // 11*74*32
    const unsigned short* WD = (const unsigned short*)(ws + B_WD);
    int blk = swz_blk(blockIdx.x, 240);
    int xt = blk % 5, y = (blk / 5) % 96, b = blk / 480;
    int x0 = xt * 64;
    int lane = threadIdx.x & 63, w = threadIdx.x >> 6;
    int pl = lane & 15, q4 = lane >> 4;
    int p = w * 16 + pl;
    int px = x0 + p;
    size_t pglob = (size_t)(b * HWc + y * Wc + px);
    size_t dbase = (size_t)b * HWc * 64;
    const float* hd = headT + pglob * 32;
    float hv[28];
#pragma unroll
    for (int i = 0; i < 7; ++i) {
        f32x4 t = *(const f32x4*)(hd + i * 4);
        hv[i * 4 + 0] = t[0]; hv[i * 4 + 1] = t[1];
        hv[i * 4 + 2] = t[2]; hv[i * 4 + 3] = t[3];
    }
    f32x4 acc[4];
#pragma unroll
    for (int cp = 0; cp < 4; ++cp) acc[cp] = (f32x4)0.f;

    const int wy0 = y - 5;          // window row origin
    const int wx0 = x0 - 5;         // window col origin

#pragma unroll
    for (int pass = 0; pass < 2; ++pass) {
        // ---- stage window (32 channels) ----
        if (pass) __syncthreads();  // WAR vs pass-0 reads
#pragma unroll
        for (int it = 0; it < 13; ++it) {
            int i = threadIdx.x + it * 256;
            if (i < 3256) {                    // 11*74*4 chunks of 16B
                int sub = i & 3;
                int c = (i >> 2) % 74;
                int r = (i >> 2) / 74;
                int gy = wy0 + r, gx = wx0 + c;
                short8 v = (short8)0;
                if ((unsigned)gy < 96u && (unsigned)gx < 320u)
                    v = *(const short8*)(depthT + ((size_t)(b * HWc + gy * Wc + gx)) * 64 + pass * 32 + sub * 8);
                int byte = (((r * 74 + c) * 64) + sub * 16) ^ ((c & 6) << 3);
                *(short8*)((char*)vls + byte) = v;
            }
        }
        __syncthreads();
        // ---- 9 kernel points ----
#pragma unroll
        for (int kk = 0; kk < 9; ++kk) {
            float dyv = hv[2 * kk], dxv = hv[2 * kk + 1], sm = hv[18 + kk];
            float m = 1.f / (1.f + __expf(-sm));
            float py  = (float)(y + kk / 3 - 1) + dyv;
            float pxf = (float)(px + kk % 3 - 1) + dxv;
            float y0f = floorf(py), x0f = floorf(pxf);
            float wy = py - y0f, wx = pxf - x0f;
            int iy0 = (int)y0f, ix0 = (int)x0f;
            bool vy0 = (unsigned)iy0 < 96u, vy1 = (unsigned)(iy0 + 1) < 96u;
            bool vx0 = (unsigned)ix0 < 320u, vx1 = (unsigned)(ix0 + 1) < 320u;
            int cy0 = min(max(iy0, 0), 95),  cy1 = min(max(iy0 + 1, 0), 95);
            int cx0 = min(max(ix0, 0), 319), cx1 = min(max(ix0 + 1, 0), 319);
            float w00 = (vy0 && vx0) ? (1.f - wy) * (1.f - wx) * m : 0.f;
            float w01 = (vy0 && vx1) ? (1.f - wy) * wx * m : 0.f;
            float w10 = (vy1 && vx0) ? wy * (1.f - wx) * m : 0.f;
            float w11 = (vy1 && vx1) ? wy * wx * m : 0.f;
            // in-window iff iy0 in [y-5, y+4] and ix0 in [x0-5, x0+67]
            bool inw = ((unsigned)(iy0 - wy0) <= 9u) && ((unsigned)(ix0 - wx0) <= 72u);
            // clamped local coords (bogus lanes read slot 0 harmlessly)
            int lr0 = min(max(cy0 - wy0, 0), 10), lr1 = min(max(cy1 - wy0, 0), 10);
            int lc0 = min(max(cx0 - wx0, 0), 73), lc1 = min(max(cx1 - wx0, 0), 73);
            int qb = q4 * 16;
            short8 f00 = *(const short8*)((const char*)vls + ((((lr0 * 74 + lc0) * 64) + qb) ^ ((lc0 & 6) << 3)));
            short8 f01 = *(const short8*)((const char*)vls + ((((lr0 * 74 + lc1) * 64) + qb) ^ ((lc1 & 6) << 3)));
            short8 f10 = *(const short8*)((const char*)vls + ((((lr1 * 74 + lc0) * 64) + qb) ^ ((lc0 & 6) << 3)));
            short8 f11 = *(const short8*)((const char*)vls + ((((lr1 * 74 + lc1) * 64) + qb) ^ ((lc1 & 6) << 3)));
            if (!__all(inw)) {                 // rare: offsets beyond +-4
                if (!inw) {
                    const unsigned short* bp = depthT + dbase + pass * 32 + q4 * 8;
                    f00 = *(const short8*)(bp + (size_t)(cy0 * Wc + cx0) * 64);
                    f01 = *(const short8*)(bp + (size_t)(cy0 * Wc + cx1) * 64);
                    f10 = *(const short8*)(bp + (size_t)(cy1 * Wc + cx0) * 64);
                    f11 = *(const short8*)(bp + (size_t)(cy1 * Wc + cx1) * 64);
                }
            }
            unsigned short vv[8];
#pragma unroll
            for (int j = 0; j < 8; ++j) {
                float v = w00 * bf2f((unsigned short)f00[j]) + w01 * bf2f((unsigned short)f01[j])
                        + w10 * bf2f((unsigned short)f10[j]) + w11 * bf2f((unsigned short)f11[j]);
                vv[j] = f2bf(v);
            }
            short8 bfr = *(short8*)vv;
#pragma unroll
            for (int cp = 0; cp < 4; ++cp) {
                short8 afr = *(const short8*)(WD + ((kk * 64 + cp * 16 + pl) * 64 + pass * 32 + q4 * 8));
                acc[cp] = __builtin_amdgcn_mfma_f32_16x16x32_bf16(afr, bfr, acc[cp], 0, 0, 0);
            }
        }
    }
    // epilogue: fdrelu = relu(acc + bd + depth) -> bf16 [pix][64]
#pragma unroll
    for (int cp = 0; cp < 4; ++cp) {
        int co0 = cp * 16 + q4 * 4;
        f32x4 bdv = *(const f32x4*)(bd + co0);
        uint2 dres = *(const uint2*)(depthT + pglob * 64 + co0);   // 4 bf16 residual
        unsigned short d4[4] = { (unsigned short)(dres.x & 0xffff), (unsigned short)(dres.x >> 16),
                                 (unsigned short)(dres.y & 0xffff), (unsigned short)(dres.y >> 16) };
        unsigned short h4[4];
#pragma unroll
        for (int j = 0; j < 4; ++j) {
            float r = acc[cp][j] + bdv[j] + bf2f(d4[j]);
            h4[j] = f2bf(fmaxf(r, 0.f));
        }
        uint2 u;
        u.x = (unsigned)h4[0] | ((unsigned)h4[1] << 16);
        u.y = (unsigned)h4[2] | ((unsigned)h4[3] << 16);
        *(uint2*)(fdreluT + pglob * 64 + co0) = u;
    }
}

// ---------------- convf: 128->64 + BN + relu -> hT  (4-row blocks) ----------------
__global__ __launch_bounds__(256) void convf_m(const unsigned short* __restrict__ fdreluT,
                                               const unsigned short* __restrict__ rgbT,
                                               const char* __restrict__ ws,
                                               unsigned short* __restrict__ hT) {
    __shared__ __align__(16) unsigned short xls[6 * 66 * 64];
    const unsigned short* WF = (const unsigned short*)(ws + B_WF);
    const float* AB = (const float*)(ws + B_AB);
    int blk = swz_blk(blockIdx.x, 60);
    int xt = blk % 5, yt = (blk / 5) % 24, b = blk / 120;
    int x0 = xt * 64, y0 = yt * 4;
    int lane = threadIdx.x & 63, w = threadIdx.x >> 6;
    int pl = lane & 15, q4 = lane >> 4;
    int p = w * 16 + pl;
    f32x4 acc[4][4];
#pragma unroll
    for (int r = 0; r < 4; ++r)
#pragma unroll
        for (int cp = 0; cp < 4; ++cp) acc[r][cp] = (f32x4)0.f;
#pragma unroll
    for (int half = 0; half < 2; ++half) {
        if (half) __syncthreads();
        stage6(half ? rgbT : fdreluT, b, y0, x0, xls, half != 0);
        __syncthreads();
        const unsigned short* Wh = WF + half * 36864;
#pragma unroll
        for (int kk = 0; kk < 9; ++kk) {
            int dy = kk / 3, dx = kk % 3;
            int xx = p + dx;
#pragma unroll
            for (int ch = 0; ch < 2; ++ch) {
                short8 bfr[4];
#pragma unroll
                for (int r = 0; r < 4; ++r) bfr[r] = read_b6(xls, dy + r, xx, ch * 32 + q4 * 8);
#pragma unroll
                for (int cp = 0; cp < 4; ++cp) {
                    short8 afr = *(const short8*)(Wh + ((kk * 64 + cp * 16 + pl) * 64 + ch * 32 + q4 * 8));
#pragma unroll
                    for (int r = 0; r < 4; ++r)
                        acc[r][cp] = __builtin_amdgcn_mfma_f32_16x16x32_bf16(afr, bfr[r], acc[r][cp], 0, 0, 0);
                }
            }
        }
    }
#pragma unroll
    for (int r = 0; r < 4; ++r) {
        size_t pglob = (size_t)(b * HWc + (y0 + r) * Wc + x0 + p);
#pragma unroll
        for (int cp = 0; cp < 4; ++cp) {
            int co0 = cp * 16 + q4 * 4;
            f32x4 a2 = *(const f32x4*)(AB + 128 + co0);
            f32x4 b2 = *(const f32x4*)(AB + 192 + co0);
            unsigned short h4[4];
#pragma unroll
            for (int j = 0; j < 4; ++j) h4[j] = f2bf(fmaxf(fmaf(acc[r][cp][j], a2[j], b2[j]), 0.f));
            uint2 u;
            u.x = (unsigned)h4[0] | ((unsigned)h4[1] << 16);
            u.y = (unsigned)h4[2] | ((unsigned)h4[3] << 16);
            *(uint2*)(hT + pglob * 64 + co0) = u;
        }
    }
}

// ---------------- conv_out: 64->1 ----------------
__global__ __launch_bounds__(256) void convo_m(const unsigned short* __restrict__ hT,
                                               const float* __restrict__ wo,
                                               const float* __restrict__ bo,
                                               float* __restrict__ out) {
    __shared__ float wl[576];
    for (int i = threadIdx.x; i < 576; i += 256) wl[i] = wo[i];
    __syncthreads();
    int p = swz_blk(blockIdx.x, 60) * 256 + threadIdx.x;   // 0..122879
    int xw = p % Wc, rem = p / Wc, y = rem % Hc, b = rem / Hc;
    float acc = bo[0];
#pragma unroll
    for (int kk = 0; kk < 9; ++kk) {
        int iy = y + kk / 3 - 1, ix = xw + kk % 3 - 1;
        if ((unsigned)iy < 96u && (unsigned)ix < 320u) {
            const unsigned short* base = hT + ((size_t)(b * HWc + iy * Wc + ix)) * 64;
#pragma unroll
            for (int g = 0; g < 8; ++g) {
                short8 v = *(const short8*)(base + g * 8);
#pragma unroll
                for (int j = 0; j < 8; ++j)
                    acc = fmaf(bf2f((unsigned short)v[j]), wl[(g * 8 + j) * 9 + kk], acc);
            }
        }
    }
    out[p] = acc;
}

// ---------------- launch ----------------
extern "C" void kernel_launch(void* const* d_in, const int* in_sizes, int n_in,
                              void* d_out, int out_size, void* d_ws, size_t ws_size,
                              hipStream_t stream) {
    const float* feat_rgb   = (const float*)d_in[0];
    const float* feat_depth = (const float*)d_in[1];
    const float* w_off1 = (const float*)d_in[2];
    const float* b_off1 = (const float*)d_in[3];
    const float* g1  = (const float*)d_in[4];
    const float* be1 = (const float*)d_in[5];
    const float* m1  = (const float*)d_in[6];
    const float* v1  = (const float*)d_in[7];
    const float* w_off2 = (const float*)d_in[8];
    const float* b_off2 = (const float*)d_in[9];
    const float* w_def  = (const float*)d_in[10];
    const float* b_def  = (const float*)d_in[11];
    const float* w_f1   = (const float*)d_in[12];
    const float* b_f1   = (const float*)d_in[13];
    const float* g2  = (const float*)d_in[14];
    const float* be2 = (const float*)d_in[15];
    const float* m2  = (const float*)d_in[16];
    const float* v2  = (const float*)d_in[17];
    const float* w_out = (const float*)d_in[18];
    const float* b_out = (const float*)d_in[19];
    (void)in_sizes; (void)n_in; (void)out_size; (void)ws_size;

    char* ws = (char*)d_ws;
    unsigned short* rgbT   = (unsigned short*)(ws + B_RGBT);
    unsigned short* depthT = (unsigned short*)(ws + B_DEPT);
    unsigned short* tT     = (unsigned short*)(ws + B_TT);
    float*          headT  = (float*)(ws + B_HEAD);
    unsigned short* fdreluT = tT;       // reuse (tT dead after conv2)
    unsigned short* hT      = depthT;   // reuse (depthT dead after mdcn)

    prep_w<<<64, 256, 0, stream>>>(w_off1, b_off1, g1, be1, m1, v1,
                                   w_off2, w_def, w_f1, b_f1, g2, be2, m2, v2, ws);
    prep_x<<<(NPIX * 8 + 255) / 256, 256, 0, stream>>>(feat_rgb, feat_depth, rgbT, depthT);
    conv1_m<<<480, 256, 0, stream>>>(rgbT, ws, tT);
    conv2_m<<<480, 256, 0, stream>>>(ws, b_off2, headT, tT);
    mdcn_l <<<1920, 256, 0, stream>>>(depthT, headT, ws, b_def, fdreluT);
    convf_m<<<480, 256, 0, stream>>>(fdreluT, rgbT, ws, hT);
    convo_m<<<480, 256, 0, stream>>>(hT, w_out, b_out, (float*)d_out);
}